// Round 2
// baseline (195.359 us; speedup 1.0000x reference)
//
#include <hip/hip_runtime.h>

#define LMBDA 0.001f
#define NS_SY 4     // NS iters for inv(sy)
#define NS_G  5     // NS iters for inv(G1), Frobenius alpha
#define NS_SX 5     // NS iters for inv(sx)
#define OUTER 3     // outer Richardson iters
#define LDP 68      // padded stride

// workspace layout (float offsets)
#define WS_A    0        // 64*256 (atomic-accumulated)
#define WS_FY   16384    // 64*256 (atomic-accumulated)
#define WS_T1   32768
#define WS_R2   36864
#define WS_R4   40960
#define WS_C    45056
#define WS_FYAT 49152
#define WS_FLAGS 53248   // ints: [0]=A tiles done (108) [1]=Fy tiles done (108) [2]=prep done (3)

#define COMP(v,q) ((q)==0?(v).x:((q)==1?(v).y:((q)==2?(v).z:(v).w)))

// row-style: a[4][2] += A[4ti+r][:] * B[:][2tj+c]
template<int SA, int SB>
__device__ __forceinline__ void mm64r(const float* __restrict__ A,
                                      const float* __restrict__ B,
                                      int ti, int tj, float a[4][2]) {
    #pragma unroll 4
    for (int k = 0; k < 64; k += 4) {
        float4 av[4];
        #pragma unroll
        for (int r = 0; r < 4; ++r) av[r] = *(const float4*)&A[(4 * ti + r) * SA + k];
        #pragma unroll
        for (int q = 0; q < 4; ++q) {
            float2 bv = *(const float2*)&B[(k + q) * SB + 2 * tj];
            #pragma unroll
            for (int r = 0; r < 4; ++r) {
                float x = COMP(av[r], q);
                a[r][0] = fmaf(x, bv.x, a[r][0]);
                a[r][1] = fmaf(x, bv.y, a[r][1]);
            }
        }
    }
}

// dot-style: a[4][2] += A[4ti+r][:] . B[2tj+c][:]  (both row-major along m)
template<int SA, int SB>
__device__ __forceinline__ void mmdot(const float* __restrict__ A,
                                      const float* __restrict__ B,
                                      int ti, int tj, float a[4][2]) {
    #pragma unroll 4
    for (int m = 0; m < 64; m += 4) {
        float4 av[4], bv[2];
        #pragma unroll
        for (int r = 0; r < 4; ++r) av[r] = *(const float4*)&A[(4 * ti + r) * SA + m];
        #pragma unroll
        for (int c = 0; c < 2; ++c) bv[c] = *(const float4*)&B[(2 * tj + c) * SB + m];
        #pragma unroll
        for (int r = 0; r < 4; ++r)
            #pragma unroll
            for (int c = 0; c < 2; ++c)
                a[r][c] += av[r].x * bv[c].x + av[r].y * bv[c].y
                         + av[r].z * bv[c].z + av[r].w * bv[c].w;
    }
}

// Newton-Schulz: X <- X(2I - M X), X0 = alpha*I. sM stride SM; sX pad LDP; sY flat
template<int SM>
__device__ __forceinline__ void ns_invert(const float* sM, float* sX, float* sY,
                                          int iters, int ti, int tj,
                                          int tid, float alpha)
{
    for (int idx = tid; idx < 4096; idx += 512) {
        int i = idx >> 6, j = idx & 63;
        sX[i * LDP + j] = (i == j) ? alpha : 0.f;
    }
    __syncthreads();
    for (int it = 0; it < iters; ++it) {
        float y[4][2] = {};
        mm64r<SM, LDP>(sM, sX, ti, tj, y);          // Y = M*X
        #pragma unroll
        for (int r = 0; r < 4; ++r)
            *(float2*)&sY[(4 * ti + r) * 64 + 2 * tj] = make_float2(y[r][0], y[r][1]);
        __syncthreads();
        float z[4][2] = {};
        mm64r<LDP, 64>(sX, sY, ti, tj, z);          // Z = X*Y
        __syncthreads();
        #pragma unroll
        for (int r = 0; r < 4; ++r) {
            float2 xv = *(const float2*)&sX[(4 * ti + r) * LDP + 2 * tj];
            xv.x = 2.f * xv.x - z[r][0];
            xv.y = 2.f * xv.y - z[r][1];
            *(float2*)&sX[(4 * ti + r) * LDP + 2 * tj] = xv;
        }
        __syncthreads();
    }
}

// ---- device-scope producer/consumer handoff ------------------------------
__device__ __forceinline__ void wait_ge(int* flag, int target, int tid) {
    if (tid == 0) {
        while (__hip_atomic_load(flag, __ATOMIC_ACQUIRE, __HIP_MEMORY_SCOPE_AGENT) < target)
            __builtin_amdgcn_s_sleep(2);
    }
    __syncthreads();
    __threadfence();
}

__device__ __forceinline__ void signal_one(int* flag, int tid) {
    __syncthreads();
    __threadfence();
    if (tid == 0)
        (void)__hip_atomic_fetch_add(flag, 1, __ATOMIC_RELEASE, __HIP_MEMORY_SCOPE_AGENT);
}

// ---------------- single fused kernel, 220 co-resident blocks, 512 thr ----
// 0..215 : GEMM tiles (gx=bid&7 -> mat/m0, gy=bid>>3 over 27 k-strides)
// 216: b0 sy chain   217: b2 sx chain   218: b3 FyAT (waits all gemm)
// 219: solve = G1 + Frobenius + NS(G1) + Richardson (waits A, then preps)
__global__ __launch_bounds__(512, 2) void fused_fmnet(
    const float* __restrict__ fx, const float* __restrict__ fy,
    const float* __restrict__ ex, const float* __restrict__ ey,
    const float* __restrict__ tx, const float* __restrict__ ty,
    const float* __restrict__ sx, const float* __restrict__ sy,
    float* __restrict__ ws, float* __restrict__ out)
{
    extern __shared__ __align__(16) float lds[];
    int* flags = (int*)(ws + WS_FLAGS);
    const int tid = threadIdx.x;
    const int ti = tid >> 5, tj = tid & 31;   // ti 0..15 (rows 4ti+r), tj 0..31 (cols 2tj+c)
    const int bid = blockIdx.x;

    if (bid < 216) {
        // ---------------- GEMM: one 64x64 (mat,m0) tile, k-strided by gy ----
        float* sT = lds;            // sT[v][k] (transposed stage)
        float* sF = lds + 4352;     // sF[v][m]
        const int gx = bid & 7, gy = bid >> 3;
        const int mat = gx >> 2;
        const int m0 = (gx & 3) << 6;
        const float* __restrict__ T = mat ? ty : tx;
        const float* __restrict__ F = mat ? fy : fx;
        float* __restrict__ Out = ws + (mat ? WS_FY : WS_A);

        float acc[4][2] = {};
        for (int sc = gy; sc * 64 < 5000; sc += 27) {
            const int v0 = sc << 6;
            int vlen = 5000 - v0; if (vlen > 64) vlen = 64;   // 64 or 8
            #pragma unroll
            for (int w = 0; w < 2; ++w) {
                const int fidx = tid + (w << 9);
                const int row = fidx >> 4, q = fidx & 15;
                const int vv = q << 2;
                if (vv < vlen) {   // sT[vv+i][row] = T[row, v0+vv+i]
                    float4 val = *(const float4*)(T + (size_t)row * 5000 + v0 + vv);
                    sT[(vv + 0) * LDP + row] = val.x;
                    sT[(vv + 1) * LDP + row] = val.y;
                    sT[(vv + 2) * LDP + row] = val.z;
                    sT[(vv + 3) * LDP + row] = val.w;
                }
                if (row < vlen) {  // sF[row][4q..] = F[v0+row, m0+4q..]
                    *(float4*)&sF[row * LDP + (q << 2)] =
                        *(const float4*)(F + (size_t)(v0 + row) * 256 + m0 + (q << 2));
                }
            }
            __syncthreads();
            #pragma unroll 2
            for (int v = 0; v < vlen; ++v) {
                float4 av = *(const float4*)&sT[v * LDP + 4 * ti];
                float2 bv = *(const float2*)&sF[v * LDP + 2 * tj];
                acc[0][0] = fmaf(av.x, bv.x, acc[0][0]); acc[0][1] = fmaf(av.x, bv.y, acc[0][1]);
                acc[1][0] = fmaf(av.y, bv.x, acc[1][0]); acc[1][1] = fmaf(av.y, bv.y, acc[1][1]);
                acc[2][0] = fmaf(av.z, bv.x, acc[2][0]); acc[2][1] = fmaf(av.z, bv.y, acc[2][1]);
                acc[3][0] = fmaf(av.w, bv.x, acc[3][0]); acc[3][1] = fmaf(av.w, bv.y, acc[3][1]);
            }
            __syncthreads();
        }
        #pragma unroll
        for (int r = 0; r < 4; ++r)
            #pragma unroll
            for (int c = 0; c < 2; ++c)
                atomicAdd(&Out[(4 * ti + r) * 256 + m0 + 2 * tj + c], acc[r][c]);
        __syncthreads();
        __threadfence();
        if (tid == 0)
            (void)__hip_atomic_fetch_add(&flags[mat], 1, __ATOMIC_RELEASE, __HIP_MEMORY_SCOPE_AGENT);
    } else if (bid == 216) {
        // ---------------- b0: sy chain (no deps) ----------------
        float* sSy = lds;            // pad: sy, later Hinv
        float* sXx = lds + 4352;     // pad: NS X -> Sinv
        float* sYy = lds + 8704;     // flat: NS tmp
        float* sH  = lds + 12800;    // flat: H1
        float* sV  = lds + 16896;    // ey
        for (int idx = tid; idx < 1024; idx += 512) {
            int i = idx >> 4, j4 = (idx & 15) << 2;
            *(float4*)&sSy[i * LDP + j4] = *(const float4*)&sy[i * 64 + j4];
        }
        if (tid < 64) sV[tid] = ey[tid];
        __syncthreads();
        // H1 = sy^T sy (column outer-product)
        {
            float h[4][2] = {};
            for (int k = 0; k < 64; ++k) {
                float4 av = *(const float4*)&sSy[k * LDP + 4 * ti];
                float2 bv = *(const float2*)&sSy[k * LDP + 2 * tj];
                h[0][0] = fmaf(av.x, bv.x, h[0][0]); h[0][1] = fmaf(av.x, bv.y, h[0][1]);
                h[1][0] = fmaf(av.y, bv.x, h[1][0]); h[1][1] = fmaf(av.y, bv.y, h[1][1]);
                h[2][0] = fmaf(av.z, bv.x, h[2][0]); h[2][1] = fmaf(av.z, bv.y, h[2][1]);
                h[3][0] = fmaf(av.w, bv.x, h[3][0]); h[3][1] = fmaf(av.w, bv.y, h[3][1]);
            }
            #pragma unroll
            for (int r = 0; r < 4; ++r)
                *(float2*)&sH[(4 * ti + r) * 64 + 2 * tj] = make_float2(h[r][0], h[r][1]);
        }
        __syncthreads();
        ns_invert<LDP>(sSy, sXx, sYy, NS_SY, ti, tj, tid, 1.0f);   // Sinv
        // Hinv = Sinv Sinv^T -> overwrite sSy
        {
            float h[4][2] = {};
            mmdot<LDP, LDP>(sXx, sXx, ti, tj, h);
            __syncthreads();
            #pragma unroll
            for (int r = 0; r < 4; ++r)
                *(float2*)&sSy[(4 * ti + r) * LDP + 2 * tj] = make_float2(h[r][0], h[r][1]);
        }
        __syncthreads();
        // C = Hinv * (D H1)
        {
            float a[4][2] = {};
            #pragma unroll 4
            for (int k = 0; k < 64; k += 4) {
                float4 av[4];
                #pragma unroll
                for (int r = 0; r < 4; ++r) av[r] = *(const float4*)&sSy[(4 * ti + r) * LDP + k];
                #pragma unroll
                for (int q = 0; q < 4; ++q) {
                    float e = sV[k + q];
                    float2 bv = *(const float2*)&sH[(k + q) * 64 + 2 * tj];
                    bv.x *= e; bv.y *= e;
                    #pragma unroll
                    for (int r = 0; r < 4; ++r) {
                        float x = COMP(av[r], q);
                        a[r][0] = fmaf(x, bv.x, a[r][0]);
                        a[r][1] = fmaf(x, bv.y, a[r][1]);
                    }
                }
            }
            #pragma unroll
            for (int r = 0; r < 4; ++r)
                *(float2*)&ws[WS_C + (4 * ti + r) * 64 + 2 * tj] = make_float2(a[r][0], a[r][1]);
        }
        signal_one(&flags[2], tid);
    } else if (bid == 217) {
        // ---------------- b2: sx chain (no deps) ----------------
        float* sM = lds;             // pad: sx
        float* sX = lds + 4352;      // pad: P
        float* sY = lds + 8704;      // flat
        float* sV = lds + 12800;     // ex
        for (int idx = tid; idx < 1024; idx += 512) {
            int i = idx >> 4, j4 = (idx & 15) << 2;
            *(float4*)&sM[i * LDP + j4] = *(const float4*)&sx[i * 64 + j4];
        }
        if (tid < 64) sV[tid] = ex[tid];
        __syncthreads();
        ns_invert<LDP>(sM, sX, sY, NS_SX, ti, tj, tid, 1.0f);
        float aR2[4][2] = {}, aR4[4][2] = {}, aT1[4][2] = {};
        for (int k = 0; k < 64; ++k) {
            float e = sV[k], e2 = e * e;
            float4 av = *(const float4*)&sX[k * LDP + 4 * ti];
            float2 bv = *(const float2*)&sX[k * LDP + 2 * tj];
            #pragma unroll
            for (int r = 0; r < 4; ++r) {
                float p = COMP(av, r);
                aR4[r][0] = fmaf(p, bv.x, aR4[r][0]); aR4[r][1] = fmaf(p, bv.y, aR4[r][1]);
                float ep = e * p;
                aR2[r][0] = fmaf(ep, bv.x, aR2[r][0]); aR2[r][1] = fmaf(ep, bv.y, aR2[r][1]);
                float e2p = e2 * p;
                aT1[r][0] = fmaf(e2p, bv.x, aT1[r][0]); aT1[r][1] = fmaf(e2p, bv.y, aT1[r][1]);
            }
        }
        #pragma unroll
        for (int r = 0; r < 4; ++r) {
            int o = (4 * ti + r) * 64 + 2 * tj;
            *(float2*)&ws[WS_R2 + o] = make_float2(aR2[r][0], aR2[r][1]);
            *(float2*)&ws[WS_R4 + o] = make_float2(aR4[r][0], aR4[r][1]);
            *(float2*)&ws[WS_T1 + o] = make_float2(aT1[r][0], aT1[r][1]);
        }
        signal_one(&flags[2], tid);
    } else if (bid == 218) {
        // ---------------- b3: FyAT = Fy A^T (waits all gemm) ----------------
        wait_ge(&flags[0], 108, tid);
        wait_ge(&flags[1], 108, tid);
        float* sFy = lds;            // pad
        float* sAx = lds + 4352;     // pad
        float a[4][2] = {};
        for (int ch = 0; ch < 4; ++ch) {
            for (int idx = tid; idx < 1024; idx += 512) {
                int i = idx >> 4, m4 = (idx & 15) << 2;
                *(float4*)&sFy[i * LDP + m4] = *(const float4*)&ws[WS_FY + i * 256 + (ch << 6) + m4];
                *(float4*)&sAx[i * LDP + m4] = *(const float4*)&ws[WS_A  + i * 256 + (ch << 6) + m4];
            }
            __syncthreads();
            mmdot<LDP, LDP>(sFy, sAx, ti, tj, a);
            __syncthreads();
        }
        #pragma unroll
        for (int r = 0; r < 4; ++r)
            *(float2*)&ws[WS_FYAT + (4 * ti + r) * 64 + 2 * tj] = make_float2(a[r][0], a[r][1]);
        signal_one(&flags[2], tid);
    } else {
        // ---------------- solve: G1 + Frobenius + NS + Richardson ----------
        float* cM1   = lds;              // flat (G1 during prep)
        float* cR2   = lds + 4096;      // flat
        float* cR4   = lds + 8192;      // flat
        float* cGinv = lds + 12288;     // flat
        float* sE    = lds + 16384;     // flat (NS tmp Y during NS)
        float* sX    = lds + 20480;     // pad  (NS X during NS)
        float* cC    = lds + 24832;     // pad  (A-chunk stage during G1)
        float* sW    = lds + 29184;     // pad  (Frobenius scratch early)

        wait_ge(&flags[0], 108, tid);    // A complete
        // G1 = A A^T via 4 column-chunk syrks
        float g[4][2] = {};
        for (int ch = 0; ch < 4; ++ch) {
            for (int idx = tid; idx < 1024; idx += 512) {
                int i = idx >> 4, m4 = (idx & 15) << 2;
                *(float4*)&cC[i * LDP + m4] =
                    *(const float4*)&ws[WS_A + i * 256 + (ch << 6) + m4];
            }
            __syncthreads();
            mmdot<LDP, LDP>(cC, cC, ti, tj, g);
            __syncthreads();
        }
        #pragma unroll
        for (int r = 0; r < 4; ++r)
            *(float2*)&cM1[(4 * ti + r) * 64 + 2 * tj] = make_float2(g[r][0], g[r][1]);
        __syncthreads();
        // Frobenius-optimal alpha = tr(G1)/||G1||_F^2
        if (tid < 64) {
            float s = 0.f;
            for (int j4 = 0; j4 < 64; j4 += 4) {
                float4 v = *(const float4*)&cM1[tid * 64 + j4];
                s += v.x * v.x + v.y * v.y + v.z * v.z + v.w * v.w;
            }
            sW[tid] = s;
            sW[64 + tid] = cM1[tid * 64 + tid];
        }
        __syncthreads();
        float f2 = 0.f, tr = 0.f;
        for (int i = 0; i < 64; ++i) { f2 += sW[i]; tr += sW[64 + i]; }
        ns_invert<64>(cM1, sX, sE, NS_G, ti, tj, tid, tr / f2);
        // copy Ginv (pad sX) -> cGinv (flat)
        for (int idx = tid; idx < 1024; idx += 512) {
            int i = idx >> 4, j4 = (idx & 15) << 2;
            *(float4*)&cGinv[i * 64 + j4] = *(const float4*)&sX[i * LDP + j4];
        }
        wait_ge(&flags[2], 3, tid);      // b0, b2, b3 done (barrier orders the copy too)
        // cM1 = G1 + lambda*T1 (in place); stage cR2/cR4/cC
        for (int idx = tid; idx < 1024; idx += 512) {
            int i = idx >> 4, j4 = (idx & 15) << 2;
            int o = i * 64 + j4;
            float4 gv = *(const float4*)&cM1[o];
            float4 t = *(const float4*)&ws[WS_T1 + o];
            gv.x = fmaf(LMBDA, t.x, gv.x); gv.y = fmaf(LMBDA, t.y, gv.y);
            gv.z = fmaf(LMBDA, t.z, gv.z); gv.w = fmaf(LMBDA, t.w, gv.w);
            *(float4*)&cM1[o] = gv;
            *(float4*)&cR2[o] = *(const float4*)&ws[WS_R2 + o];
            *(float4*)&cR4[o] = *(const float4*)&ws[WS_R4 + o];
            *(float4*)&cC[i * LDP + j4] = *(const float4*)&ws[WS_C + o];
        }
        float4 eyv = *(const float4*)&ey[4 * ti];
        float eyr[4] = {eyv.x, eyv.y, eyv.z, eyv.w};
        float leyr[4];
        #pragma unroll
        for (int r = 0; r < 4; ++r) leyr[r] = LMBDA * eyr[r];

        float fyr[4][2], xreg[4][2];
        #pragma unroll
        for (int r = 0; r < 4; ++r) {
            float2 v = *(const float2*)&ws[WS_FYAT + (4 * ti + r) * 64 + 2 * tj];
            fyr[r][0] = v.x; fyr[r][1] = v.y;
            *(float2*)&sX[(4 * ti + r) * LDP + 2 * tj] = make_float2(0.f, 0.f);
            xreg[r][0] = 0.f; xreg[r][1] = 0.f;
        }
        __syncthreads();

        float E1[4][2];
        for (int it = 0; it < OUTER; ++it) {
            // grp1: Sm=X*M1, S2=X*R2, S4=X*R4 (shared A-reads)
            {
                float Sm[4][2] = {}, S2[4][2] = {}, S4[4][2] = {};
                #pragma unroll 2
                for (int k = 0; k < 64; k += 4) {
                    float4 av[4];
                    #pragma unroll
                    for (int r = 0; r < 4; ++r)
                        av[r] = *(const float4*)&sX[(4 * ti + r) * LDP + k];
                    #pragma unroll
                    for (int q = 0; q < 4; ++q) {
                        float2 mv = *(const float2*)&cM1[(k + q) * 64 + 2 * tj];
                        float2 qv = *(const float2*)&cR2[(k + q) * 64 + 2 * tj];
                        float2 rv = *(const float2*)&cR4[(k + q) * 64 + 2 * tj];
                        #pragma unroll
                        for (int r = 0; r < 4; ++r) {
                            float x = COMP(av[r], q);
                            Sm[r][0] = fmaf(x, mv.x, Sm[r][0]); Sm[r][1] = fmaf(x, mv.y, Sm[r][1]);
                            S2[r][0] = fmaf(x, qv.x, S2[r][0]); S2[r][1] = fmaf(x, qv.y, S2[r][1]);
                            S4[r][0] = fmaf(x, rv.x, S4[r][0]); S4[r][1] = fmaf(x, rv.y, S4[r][1]);
                        }
                    }
                }
                #pragma unroll
                for (int r = 0; r < 4; ++r) {
                    float2 e2v;
                    e2v.x = LMBDA * fmaf(eyr[r], S4[r][0], -S2[r][0]);
                    e2v.y = LMBDA * fmaf(eyr[r], S4[r][1], -S2[r][1]);
                    *(float2*)&sE[(4 * ti + r) * 64 + 2 * tj] = e2v;
                    E1[r][0] = fmaf(-leyr[r], S2[r][0], Sm[r][0]);
                    E1[r][1] = fmaf(-leyr[r], S2[r][1], Sm[r][1]);
                }
            }
            __syncthreads();
            // grp2: Z = C*E2 ; W = FyAT - E1 - Z
            {
                float Z[4][2] = {};
                mm64r<LDP, 64>(cC, sE, ti, tj, Z);
                #pragma unroll
                for (int r = 0; r < 4; ++r) {
                    float2 w;
                    w.x = fyr[r][0] - E1[r][0] - Z[r][0];
                    w.y = fyr[r][1] - E1[r][1] - Z[r][1];
                    *(float2*)&sW[(4 * ti + r) * LDP + 2 * tj] = w;
                }
            }
            __syncthreads();
            // grp3: dX = W*Ginv ; X += dX
            {
                float dX[4][2] = {};
                mm64r<LDP, 64>(sW, cGinv, ti, tj, dX);
                #pragma unroll
                for (int r = 0; r < 4; ++r) {
                    xreg[r][0] += dX[r][0]; xreg[r][1] += dX[r][1];
                    float2 v = make_float2(xreg[r][0], xreg[r][1]);
                    *(float2*)&sX[(4 * ti + r) * LDP + 2 * tj] = v;
                    if (it == OUTER - 1)
                        *(float2*)&out[(4 * ti + r) * 64 + 2 * tj] = v;
                }
            }
            if (it == OUTER - 1) break;
            __syncthreads();
        }
    }
}

extern "C" void kernel_launch(void* const* d_in, const int* in_sizes, int n_in,
                              void* d_out, int out_size, void* d_ws, size_t ws_size,
                              hipStream_t stream) {
    (void)in_sizes; (void)n_in; (void)out_size; (void)ws_size;
    const float* fx = (const float*)d_in[0];
    const float* fy = (const float*)d_in[1];
    const float* ex = (const float*)d_in[2];
    const float* ey = (const float*)d_in[3];
    const float* tx = (const float*)d_in[4];
    const float* ty = (const float*)d_in[5];
    const float* sx = (const float*)d_in[6];
    const float* sy = (const float*)d_in[7];
    float* ws = (float*)d_ws;
    float* out = (float*)d_out;

    (void)hipFuncSetAttribute((const void*)fused_fmnet,
                              hipFuncAttributeMaxDynamicSharedMemorySize, 134144);

    // zero A/Fy accumulators + flags
    (void)hipMemsetAsync(d_ws, 0, 2 * 64 * 256 * sizeof(float), stream);
    (void)hipMemsetAsync((char*)d_ws + (size_t)WS_FLAGS * sizeof(float), 0, 64, stream);
    fused_fmnet<<<220, 512, 134144, stream>>>(fx, fy, ex, ey, tx, ty, sx, sy, ws, out);
}

// Round 4
// 190.359 us; speedup vs baseline: 1.0263x; 1.0263x over previous
//
#include <hip/hip_runtime.h>

#define LMBDA 0.001f
#define NS_SY 4     // NS iters for inv(sy)
#define NS_G  5     // NS iters for inv(G1), Frobenius alpha
#define NS_SX 5     // NS iters for inv(sx)
#define OUTER 3     // outer Richardson iters
#define LDP 68      // padded stride

// workspace layout (float offsets) — [0, 40960) is memset to 0 each launch
#define WS_A    0        // 64*256 (atomic-accumulated)
#define WS_FY   16384    // 64*256 (atomic-accumulated)
#define WS_G1   32768    // 64*64  (atomic-accumulated by 4 chunk blocks)
#define WS_FYAT 36864    // 64*64  (atomic-accumulated by 4 chunk blocks)
#define WS_T1   40960
#define WS_R2   45056
#define WS_R4   49152
#define WS_C    53248
#define WS_FLAGS 57344   // ints: [0..7] per-gx gemm cnt (27) [8] G1 chunks (4) [9] preps (6)

#define FMA4(ar, xs, b) { ar[0]=fmaf((xs),(b).x,ar[0]); ar[1]=fmaf((xs),(b).y,ar[1]); \
                          ar[2]=fmaf((xs),(b).z,ar[2]); ar[3]=fmaf((xs),(b).w,ar[3]); }

// C-tile += A[4ti..][:] * B[:][4tj..]; all f4 (b128) LDS reads
template<int SA, int SB>
__device__ __forceinline__ void mm64(const float* __restrict__ A,
                                     const float* __restrict__ B,
                                     int ti, int tj, float a[4][4]) {
    #pragma unroll 4
    for (int k = 0; k < 64; k += 4) {
        float4 av0 = *(const float4*)&A[(4 * ti + 0) * SA + k];
        float4 av1 = *(const float4*)&A[(4 * ti + 1) * SA + k];
        float4 av2 = *(const float4*)&A[(4 * ti + 2) * SA + k];
        float4 av3 = *(const float4*)&A[(4 * ti + 3) * SA + k];
        float4 b0 = *(const float4*)&B[(k + 0) * SB + 4 * tj];
        float4 b1 = *(const float4*)&B[(k + 1) * SB + 4 * tj];
        float4 b2 = *(const float4*)&B[(k + 2) * SB + 4 * tj];
        float4 b3 = *(const float4*)&B[(k + 3) * SB + 4 * tj];
        FMA4(a[0], av0.x, b0); FMA4(a[0], av0.y, b1); FMA4(a[0], av0.z, b2); FMA4(a[0], av0.w, b3);
        FMA4(a[1], av1.x, b0); FMA4(a[1], av1.y, b1); FMA4(a[1], av1.z, b2); FMA4(a[1], av1.w, b3);
        FMA4(a[2], av2.x, b0); FMA4(a[2], av2.y, b1); FMA4(a[2], av2.z, b2); FMA4(a[2], av2.w, b3);
        FMA4(a[3], av3.x, b0); FMA4(a[3], av3.y, b1); FMA4(a[3], av3.z, b2); FMA4(a[3], av3.w, b3);
    }
}

// dot-style 4x4: a[r][c] += A[4ti+r][:] . B[4tj+c][:]
template<int SA, int SB>
__device__ __forceinline__ void mmdot(const float* __restrict__ A,
                                      const float* __restrict__ B,
                                      int ti, int tj, float a[4][4]) {
    #pragma unroll 4
    for (int m = 0; m < 64; m += 4) {
        float4 av[4], bv[4];
        #pragma unroll
        for (int r = 0; r < 4; ++r) av[r] = *(const float4*)&A[(4 * ti + r) * SA + m];
        #pragma unroll
        for (int c = 0; c < 4; ++c) bv[c] = *(const float4*)&B[(4 * tj + c) * SB + m];
        #pragma unroll
        for (int r = 0; r < 4; ++r)
            #pragma unroll
            for (int c = 0; c < 4; ++c)
                a[r][c] += av[r].x * bv[c].x + av[r].y * bv[c].y
                         + av[r].z * bv[c].z + av[r].w * bv[c].w;
    }
}

// Newton-Schulz: X <- X(2I - M X), X0 = alpha*I. sM stride SM; sX pad; sY flat
template<int SM>
__device__ __forceinline__ void ns_invert(const float* sM, float* sX, float* sY,
                                          int iters, int ti, int tj,
                                          int tid, float alpha)
{
    for (int idx = tid; idx < 4096; idx += 256) {
        int i = idx >> 6, j = idx & 63;
        sX[i * LDP + j] = (i == j) ? alpha : 0.f;
    }
    __syncthreads();
    for (int it = 0; it < iters; ++it) {
        float y[4][4] = {};
        mm64<SM, LDP>(sM, sX, ti, tj, y);          // Y = M*X
        #pragma unroll
        for (int r = 0; r < 4; ++r) {
            float4 v = {y[r][0], y[r][1], y[r][2], y[r][3]};
            *(float4*)&sY[(4 * ti + r) * 64 + 4 * tj] = v;
        }
        __syncthreads();
        float z[4][4] = {};
        mm64<LDP, 64>(sX, sY, ti, tj, z);           // Z = X*Y
        __syncthreads();
        #pragma unroll
        for (int r = 0; r < 4; ++r) {
            float4 xv = *(const float4*)&sX[(4 * ti + r) * LDP + 4 * tj];
            xv.x = 2.f * xv.x - z[r][0];
            xv.y = 2.f * xv.y - z[r][1];
            xv.z = 2.f * xv.z - z[r][2];
            xv.w = 2.f * xv.w - z[r][3];
            *(float4*)&sX[(4 * ti + r) * LDP + 4 * tj] = xv;
        }
        __syncthreads();
    }
}

// ---- device-scope producer/consumer handoff ------------------------------
__device__ __forceinline__ void wait_ge(int* flag, int target, int tid) {
    if (tid == 0) {
        while (__hip_atomic_load(flag, __ATOMIC_ACQUIRE, __HIP_MEMORY_SCOPE_AGENT) < target)
            __builtin_amdgcn_s_sleep(8);
    }
    __syncthreads();
    __threadfence();
}

__device__ __forceinline__ void signal_one(int* flag, int tid) {
    __syncthreads();
    __threadfence();
    if (tid == 0)
        (void)__hip_atomic_fetch_add(flag, 1, __ATOMIC_RELEASE, __HIP_MEMORY_SCOPE_AGENT);
}

// ---------------- single fused kernel, 227 co-resident blocks, 256 thr ----
// 0..215  : GEMM tiles (gx=bid&7 -> mat/m0, gy=bid>>3 over 27 k-strides)
// 216..219: G1 chunk ch = A_ch A_ch^T -> atomicAdd (waits flags[ch]==27)
// 220..223: FyAT chunk ch = Fy_ch A_ch^T -> atomicAdd (waits flags[ch],flags[4+ch])
// 224: b0 sy chain   225: b2 sx chain
// 226: solve = Frobenius + NS(G1) + Richardson (waits G1 chunks, then preps)
__global__ __launch_bounds__(256, 1) void fused_fmnet(
    const float* __restrict__ fx, const float* __restrict__ fy,
    const float* __restrict__ ex, const float* __restrict__ ey,
    const float* __restrict__ tx, const float* __restrict__ ty,
    const float* __restrict__ sx, const float* __restrict__ sy,
    float* __restrict__ ws, float* __restrict__ out)
{
    extern __shared__ __align__(16) float lds[];
    int* flags = (int*)(ws + WS_FLAGS);
    const int tid = threadIdx.x;
    const int ti = tid >> 4, tj = tid & 15;
    const int bid = blockIdx.x;

    if (bid < 216) {
        // ---------------- GEMM: 64x64 (mat,m0) tile, k-strided by gy ----
        float* sT = lds;            // sT[v][k] (transposed stage)
        float* sF = lds + 4352;     // sF[v][m]
        const int gx = bid & 7, gy = bid >> 3;
        const int mat = gx >> 2;
        const int m0 = (gx & 3) << 6;
        const float* __restrict__ T = mat ? ty : tx;
        const float* __restrict__ F = mat ? fy : fx;
        float* __restrict__ Out = ws + (mat ? WS_FY : WS_A);

        float acc[4][4] = {};
        for (int sc = gy; sc * 64 < 5000; sc += 27) {
            const int v0 = sc << 6;
            int vlen = 5000 - v0; if (vlen > 64) vlen = 64;   // 64 or 8
            #pragma unroll
            for (int w = 0; w < 4; ++w) {
                const int fidx = tid + (w << 8);
                const int row = fidx >> 4, q = fidx & 15;
                const int vv = q << 2;
                if (vv < vlen) {   // sT[vv+i][row] = T[row, v0+vv+i]
                    float4 val = *(const float4*)(T + (size_t)row * 5000 + v0 + vv);
                    sT[(vv + 0) * LDP + row] = val.x;
                    sT[(vv + 1) * LDP + row] = val.y;
                    sT[(vv + 2) * LDP + row] = val.z;
                    sT[(vv + 3) * LDP + row] = val.w;
                }
                if (row < vlen) {  // sF[row][4q..] = F[v0+row, m0+4q..]
                    *(float4*)&sF[row * LDP + (q << 2)] =
                        *(const float4*)(F + (size_t)(v0 + row) * 256 + m0 + (q << 2));
                }
            }
            __syncthreads();
            #pragma unroll 4
            for (int v = 0; v < vlen; ++v) {
                float4 av = *(const float4*)&sT[v * LDP + 4 * ti];
                float4 bv = *(const float4*)&sF[v * LDP + 4 * tj];
                FMA4(acc[0], av.x, bv); FMA4(acc[1], av.y, bv);
                FMA4(acc[2], av.z, bv); FMA4(acc[3], av.w, bv);
            }
            __syncthreads();
        }
        #pragma unroll
        for (int r = 0; r < 4; ++r)
            #pragma unroll
            for (int c = 0; c < 4; ++c)
                atomicAdd(&Out[(4 * ti + r) * 256 + m0 + 4 * tj + c], acc[r][c]);
        __syncthreads();
        __threadfence();
        if (tid == 0)
            (void)__hip_atomic_fetch_add(&flags[gx], 1, __ATOMIC_RELEASE, __HIP_MEMORY_SCOPE_AGENT);
    } else if (bid < 220) {
        // ---------------- G1 chunk: A_ch A_ch^T -> atomicAdd WS_G1 ----
        const int ch = bid - 216;
        wait_ge(&flags[ch], 27, tid);
        float* sA = lds;             // pad
        for (int idx = tid; idx < 1024; idx += 256) {
            int i = idx >> 4, m4 = (idx & 15) << 2;
            *(float4*)&sA[i * LDP + m4] =
                *(const float4*)&ws[WS_A + i * 256 + (ch << 6) + m4];
        }
        __syncthreads();
        float a[4][4] = {};
        mmdot<LDP, LDP>(sA, sA, ti, tj, a);
        #pragma unroll
        for (int r = 0; r < 4; ++r)
            #pragma unroll
            for (int c = 0; c < 4; ++c)
                atomicAdd(&ws[WS_G1 + (4 * ti + r) * 64 + 4 * tj + c], a[r][c]);
        __syncthreads();
        __threadfence();
        if (tid == 0)
            (void)__hip_atomic_fetch_add(&flags[8], 1, __ATOMIC_RELEASE, __HIP_MEMORY_SCOPE_AGENT);
    } else if (bid < 224) {
        // ---------------- FyAT chunk: Fy_ch A_ch^T -> atomicAdd WS_FYAT ----
        const int ch = bid - 220;
        wait_ge(&flags[ch], 27, tid);
        wait_ge(&flags[4 + ch], 27, tid);
        float* sFy = lds;            // pad
        float* sAx = lds + 4352;     // pad
        for (int idx = tid; idx < 1024; idx += 256) {
            int i = idx >> 4, m4 = (idx & 15) << 2;
            *(float4*)&sFy[i * LDP + m4] = *(const float4*)&ws[WS_FY + i * 256 + (ch << 6) + m4];
            *(float4*)&sAx[i * LDP + m4] = *(const float4*)&ws[WS_A  + i * 256 + (ch << 6) + m4];
        }
        __syncthreads();
        float a[4][4] = {};
        mmdot<LDP, LDP>(sFy, sAx, ti, tj, a);
        #pragma unroll
        for (int r = 0; r < 4; ++r)
            #pragma unroll
            for (int c = 0; c < 4; ++c)
                atomicAdd(&ws[WS_FYAT + (4 * ti + r) * 64 + 4 * tj + c], a[r][c]);
        signal_one(&flags[9], tid);
    } else if (bid == 224) {
        // ---------------- b0: sy chain (no deps) ----------------
        float* sSy = lds;            // pad: sy, later Hinv
        float* sXx = lds + 4352;     // pad: NS X -> Sinv
        float* sYy = lds + 8704;     // flat: NS tmp
        float* sH  = lds + 12800;    // flat: H1
        float* sV  = lds + 16896;    // ey
        for (int idx = tid; idx < 1024; idx += 256) {
            int i = idx >> 4, j4 = (idx & 15) << 2;
            *(float4*)&sSy[i * LDP + j4] = *(const float4*)&sy[i * 64 + j4];
        }
        if (tid < 64) sV[tid] = ey[tid];
        __syncthreads();
        // H1 = sy^T sy (column outer-product)
        {
            float h[4][4] = {};
            for (int k = 0; k < 64; ++k) {
                float4 av = *(const float4*)&sSy[k * LDP + 4 * ti];
                float4 bv = *(const float4*)&sSy[k * LDP + 4 * tj];
                FMA4(h[0], av.x, bv); FMA4(h[1], av.y, bv);
                FMA4(h[2], av.z, bv); FMA4(h[3], av.w, bv);
            }
            #pragma unroll
            for (int r = 0; r < 4; ++r) {
                float4 v = {h[r][0], h[r][1], h[r][2], h[r][3]};
                *(float4*)&sH[(4 * ti + r) * 64 + 4 * tj] = v;
            }
        }
        __syncthreads();
        ns_invert<LDP>(sSy, sXx, sYy, NS_SY, ti, tj, tid, 1.0f);   // Sinv
        // Hinv = Sinv Sinv^T -> overwrite sSy
        {
            float h[4][4] = {};
            mmdot<LDP, LDP>(sXx, sXx, ti, tj, h);
            __syncthreads();
            #pragma unroll
            for (int r = 0; r < 4; ++r) {
                float4 v = {h[r][0], h[r][1], h[r][2], h[r][3]};
                *(float4*)&sSy[(4 * ti + r) * LDP + 4 * tj] = v;
            }
        }
        __syncthreads();
        // C = Hinv * (D H1)
        {
            float a[4][4] = {};
            #pragma unroll 4
            for (int k = 0; k < 64; k += 4) {
                float4 av[4];
                #pragma unroll
                for (int r = 0; r < 4; ++r) av[r] = *(const float4*)&sSy[(4 * ti + r) * LDP + k];
                #pragma unroll
                for (int q = 0; q < 4; ++q) {
                    float e = sV[k + q];
                    float4 bv = *(const float4*)&sH[(k + q) * 64 + 4 * tj];
                    bv.x *= e; bv.y *= e; bv.z *= e; bv.w *= e;
                    float xq[4] = {av[0].x, av[1].x, av[2].x, av[3].x};
                    if (q == 1) { xq[0]=av[0].y; xq[1]=av[1].y; xq[2]=av[2].y; xq[3]=av[3].y; }
                    if (q == 2) { xq[0]=av[0].z; xq[1]=av[1].z; xq[2]=av[2].z; xq[3]=av[3].z; }
                    if (q == 3) { xq[0]=av[0].w; xq[1]=av[1].w; xq[2]=av[2].w; xq[3]=av[3].w; }
                    #pragma unroll
                    for (int r = 0; r < 4; ++r) FMA4(a[r], xq[r], bv);
                }
            }
            #pragma unroll
            for (int r = 0; r < 4; ++r) {
                float4 v = {a[r][0], a[r][1], a[r][2], a[r][3]};
                *(float4*)&ws[WS_C + (4 * ti + r) * 64 + 4 * tj] = v;
            }
        }
        signal_one(&flags[9], tid);
    } else if (bid == 225) {
        // ---------------- b2: sx chain (no deps) ----------------
        float* sM = lds;             // pad: sx
        float* sX = lds + 4352;      // pad: P
        float* sY = lds + 8704;      // flat
        float* sV = lds + 12800;     // ex
        for (int idx = tid; idx < 1024; idx += 256) {
            int i = idx >> 4, j4 = (idx & 15) << 2;
            *(float4*)&sM[i * LDP + j4] = *(const float4*)&sx[i * 64 + j4];
        }
        if (tid < 64) sV[tid] = ex[tid];
        __syncthreads();
        ns_invert<LDP>(sM, sX, sY, NS_SX, ti, tj, tid, 1.0f);
        float aR2[4][4] = {}, aR4[4][4] = {}, aT1[4][4] = {};
        for (int k = 0; k < 64; ++k) {
            float e = sV[k], e2 = e * e;
            float4 av = *(const float4*)&sX[k * LDP + 4 * ti];
            float4 bv = *(const float4*)&sX[k * LDP + 4 * tj];
            float avv[4] = {av.x, av.y, av.z, av.w};
            #pragma unroll
            for (int r = 0; r < 4; ++r) {
                FMA4(aR4[r], avv[r], bv);
                float ea = e * avv[r];
                FMA4(aR2[r], ea, bv);
                float e2a = e2 * avv[r];
                FMA4(aT1[r], e2a, bv);
            }
        }
        #pragma unroll
        for (int r = 0; r < 4; ++r) {
            int o = (4 * ti + r) * 64 + 4 * tj;
            float4 v2 = {aR2[r][0], aR2[r][1], aR2[r][2], aR2[r][3]};
            float4 v4 = {aR4[r][0], aR4[r][1], aR4[r][2], aR4[r][3]};
            float4 v1 = {aT1[r][0], aT1[r][1], aT1[r][2], aT1[r][3]};
            *(float4*)&ws[WS_R2 + o] = v2;
            *(float4*)&ws[WS_R4 + o] = v4;
            *(float4*)&ws[WS_T1 + o] = v1;
        }
        signal_one(&flags[9], tid);
    } else {
        // ---------------- solve: Frobenius + NS(G1) + Richardson ----------
        float* cM1   = lds;              // flat (G1 during NS, then M1)
        float* cR2   = lds + 4096;      // flat
        float* cR4   = lds + 8192;      // flat
        float* cGinv = lds + 12288;     // flat
        float* sE    = lds + 16384;     // flat (NS tmp Y, then E2)
        float* sX    = lds + 20480;     // pad  (NS X, then Richardson X)
        float* cC    = lds + 24832;     // pad
        float* sW    = lds + 29184;     // pad  (Frobenius scratch, then W)

        wait_ge(&flags[8], 4, tid);      // G1 complete
        for (int idx = tid; idx < 1024; idx += 256) {
            int i = idx >> 4, j4 = (idx & 15) << 2;
            *(float4*)&cM1[i * 64 + j4] = *(const float4*)&ws[WS_G1 + i * 64 + j4];
        }
        __syncthreads();
        // Frobenius-optimal alpha = tr(G1)/||G1||_F^2
        if (tid < 64) {
            float s = 0.f;
            for (int j4 = 0; j4 < 64; j4 += 4) {
                float4 v = *(const float4*)&cM1[tid * 64 + j4];
                s += v.x * v.x + v.y * v.y + v.z * v.z + v.w * v.w;
            }
            sW[tid] = s;
            sW[64 + tid] = cM1[tid * 64 + tid];
        }
        __syncthreads();
        float f2 = 0.f, tr = 0.f;
        for (int i = 0; i < 64; ++i) { f2 += sW[i]; tr += sW[64 + i]; }
        ns_invert<64>(cM1, sX, sE, NS_G, ti, tj, tid, tr / f2);
        // copy Ginv (pad sX) -> cGinv (flat)
        for (int idx = tid; idx < 1024; idx += 256) {
            int i = idx >> 4, j4 = (idx & 15) << 2;
            *(float4*)&cGinv[i * 64 + j4] = *(const float4*)&sX[i * LDP + j4];
        }
        wait_ge(&flags[9], 6, tid);      // b0, b2, 4 FyAT chunks done
        // cM1 = G1 + lambda*T1 (in place); stage cR2/cR4/cC
        for (int idx = tid; idx < 1024; idx += 256) {
            int i = idx >> 4, j4 = (idx & 15) << 2;
            int o = i * 64 + j4;
            float4 gv = *(const float4*)&cM1[o];
            float4 t = *(const float4*)&ws[WS_T1 + o];
            gv.x = fmaf(LMBDA, t.x, gv.x); gv.y = fmaf(LMBDA, t.y, gv.y);
            gv.z = fmaf(LMBDA, t.z, gv.z); gv.w = fmaf(LMBDA, t.w, gv.w);
            *(float4*)&cM1[o] = gv;
            *(float4*)&cR2[o] = *(const float4*)&ws[WS_R2 + o];
            *(float4*)&cR4[o] = *(const float4*)&ws[WS_R4 + o];
            *(float4*)&cC[i * LDP + j4] = *(const float4*)&ws[WS_C + o];
        }
        float4 eyv = *(const float4*)&ey[4 * ti];
        float eyr[4] = {eyv.x, eyv.y, eyv.z, eyv.w};
        float leyr[4];
        #pragma unroll
        for (int r = 0; r < 4; ++r) leyr[r] = LMBDA * eyr[r];

        float fyr[4][4], xreg[4][4];
        #pragma unroll
        for (int r = 0; r < 4; ++r) {
            float4 v = *(const float4*)&ws[WS_FYAT + (4 * ti + r) * 64 + 4 * tj];
            fyr[r][0] = v.x; fyr[r][1] = v.y; fyr[r][2] = v.z; fyr[r][3] = v.w;
            float4 z = {0.f, 0.f, 0.f, 0.f};
            *(float4*)&sX[(4 * ti + r) * LDP + 4 * tj] = z;
            #pragma unroll
            for (int c = 0; c < 4; ++c) xreg[r][c] = 0.f;
        }
        __syncthreads();

        float E1[4][4];
        for (int it = 0; it < OUTER; ++it) {
            // grp1: Sm=X*M1, S2=X*R2, S4=X*R4 (shared A-reads)
            {
                float Sm[4][4] = {}, S2[4][4] = {}, S4[4][4] = {};
                #pragma unroll 2
                for (int k = 0; k < 64; k += 4) {
                    float4 av[4];
                    #pragma unroll
                    for (int r = 0; r < 4; ++r)
                        av[r] = *(const float4*)&sX[(4 * ti + r) * LDP + k];
                    #pragma unroll
                    for (int q = 0; q < 4; ++q) {
                        float4 mv = *(const float4*)&cM1[(k + q) * 64 + 4 * tj];
                        float4 qv = *(const float4*)&cR2[(k + q) * 64 + 4 * tj];
                        float4 rv = *(const float4*)&cR4[(k + q) * 64 + 4 * tj];
                        float xq[4] = {av[0].x, av[1].x, av[2].x, av[3].x};
                        if (q == 1) { xq[0]=av[0].y; xq[1]=av[1].y; xq[2]=av[2].y; xq[3]=av[3].y; }
                        if (q == 2) { xq[0]=av[0].z; xq[1]=av[1].z; xq[2]=av[2].z; xq[3]=av[3].z; }
                        if (q == 3) { xq[0]=av[0].w; xq[1]=av[1].w; xq[2]=av[2].w; xq[3]=av[3].w; }
                        #pragma unroll
                        for (int r = 0; r < 4; ++r) {
                            FMA4(Sm[r], xq[r], mv);
                            FMA4(S2[r], xq[r], qv);
                            FMA4(S4[r], xq[r], rv);
                        }
                    }
                }
                #pragma unroll
                for (int r = 0; r < 4; ++r) {
                    float4 e2;
                    e2.x = LMBDA * fmaf(eyr[r], S4[r][0], -S2[r][0]);
                    e2.y = LMBDA * fmaf(eyr[r], S4[r][1], -S2[r][1]);
                    e2.z = LMBDA * fmaf(eyr[r], S4[r][2], -S2[r][2]);
                    e2.w = LMBDA * fmaf(eyr[r], S4[r][3], -S2[r][3]);
                    *(float4*)&sE[(4 * ti + r) * 64 + 4 * tj] = e2;
                    #pragma unroll
                    for (int c = 0; c < 4; ++c)
                        E1[r][c] = fmaf(-leyr[r], S2[r][c], Sm[r][c]);
                }
            }
            __syncthreads();
            // grp2: Z = C*E2 ; W = FyAT - E1 - Z
            {
                float Z[4][4] = {};
                mm64<LDP, 64>(cC, sE, ti, tj, Z);
                #pragma unroll
                for (int r = 0; r < 4; ++r) {
                    float4 w;
                    w.x = fyr[r][0] - E1[r][0] - Z[r][0];
                    w.y = fyr[r][1] - E1[r][1] - Z[r][1];
                    w.z = fyr[r][2] - E1[r][2] - Z[r][2];
                    w.w = fyr[r][3] - E1[r][3] - Z[r][3];
                    *(float4*)&sW[(4 * ti + r) * LDP + 4 * tj] = w;
                }
            }
            __syncthreads();
            // grp3: dX = W*Ginv ; X += dX
            {
                float dX[4][4] = {};
                mm64<LDP, 64>(sW, cGinv, ti, tj, dX);
                #pragma unroll
                for (int r = 0; r < 4; ++r) {
                    float4 v;
                    #pragma unroll
                    for (int c = 0; c < 4; ++c) xreg[r][c] += dX[r][c];
                    v.x = xreg[r][0]; v.y = xreg[r][1]; v.z = xreg[r][2]; v.w = xreg[r][3];
                    *(float4*)&sX[(4 * ti + r) * LDP + 4 * tj] = v;
                    if (it == OUTER - 1)
                        *(float4*)&out[(4 * ti + r) * 64 + 4 * tj] = v;
                }
            }
            if (it == OUTER - 1) break;
            __syncthreads();
        }
    }
}

extern "C" void kernel_launch(void* const* d_in, const int* in_sizes, int n_in,
                              void* d_out, int out_size, void* d_ws, size_t ws_size,
                              hipStream_t stream) {
    (void)in_sizes; (void)n_in; (void)out_size; (void)ws_size;
    const float* fx = (const float*)d_in[0];
    const float* fy = (const float*)d_in[1];
    const float* ex = (const float*)d_in[2];
    const float* ey = (const float*)d_in[3];
    const float* tx = (const float*)d_in[4];
    const float* ty = (const float*)d_in[5];
    const float* sx = (const float*)d_in[6];
    const float* sy = (const float*)d_in[7];
    float* ws = (float*)d_ws;
    float* out = (float*)d_out;

    (void)hipFuncSetAttribute((const void*)fused_fmnet,
                              hipFuncAttributeMaxDynamicSharedMemorySize, 134144);

    // zero A/Fy/G1/FyAT accumulators + flags
    (void)hipMemsetAsync(d_ws, 0, (size_t)(WS_T1) * sizeof(float), stream);
    (void)hipMemsetAsync((char*)d_ws + (size_t)WS_FLAGS * sizeof(float), 0, 64, stream);
    fused_fmnet<<<227, 256, 134144, stream>>>(fx, fy, ex, ey, tx, ty, sx, sy, ws, out);
}

// Round 5
// 182.113 us; speedup vs baseline: 1.0727x; 1.0453x over previous
//
#include <hip/hip_runtime.h>

#define LMBDA 0.001f
#define NS_SY 4     // NS iters for inv(sy) (first iter analytic)
#define NS_G  5     // NS iters for inv(G1), Frobenius alpha (first iter analytic)
#define NS_SX 5     // NS iters for inv(sx) (first iter analytic)
#define OUTER 3     // outer Richardson iters
#define LDP 68      // padded stride
#define GYS 30      // gy k-stride count (240 gemm blocks)

// workspace layout (float offsets) — [0, 40960) is memset to 0 each launch
#define WS_A    0        // 64*256 (atomic-accumulated)
#define WS_FY   16384    // 64*256 (atomic-accumulated)
#define WS_G1   32768    // 64*64  (atomic-accumulated by 4 chunk blocks)
#define WS_FYAT 36864    // 64*64  (atomic-accumulated by 4 chunk blocks)
#define WS_T1   40960
#define WS_R2   45056
#define WS_R4   49152
#define WS_C    53248
#define WS_FLAGS 57344   // ints: [0..7] per-gx gemm cnt (GYS) [8] G1 chunks (4) [9] preps (6)

#define FMA4(ar, xs, b) { ar[0]=fmaf((xs),(b).x,ar[0]); ar[1]=fmaf((xs),(b).y,ar[1]); \
                          ar[2]=fmaf((xs),(b).z,ar[2]); ar[3]=fmaf((xs),(b).w,ar[3]); }

// C-tile += A[4ti..][:] * B[:][4tj..]; all f4 (b128) LDS reads
template<int SA, int SB>
__device__ __forceinline__ void mm64(const float* __restrict__ A,
                                     const float* __restrict__ B,
                                     int ti, int tj, float a[4][4]) {
    #pragma unroll 4
    for (int k = 0; k < 64; k += 4) {
        float4 av0 = *(const float4*)&A[(4 * ti + 0) * SA + k];
        float4 av1 = *(const float4*)&A[(4 * ti + 1) * SA + k];
        float4 av2 = *(const float4*)&A[(4 * ti + 2) * SA + k];
        float4 av3 = *(const float4*)&A[(4 * ti + 3) * SA + k];
        float4 b0 = *(const float4*)&B[(k + 0) * SB + 4 * tj];
        float4 b1 = *(const float4*)&B[(k + 1) * SB + 4 * tj];
        float4 b2 = *(const float4*)&B[(k + 2) * SB + 4 * tj];
        float4 b3 = *(const float4*)&B[(k + 3) * SB + 4 * tj];
        FMA4(a[0], av0.x, b0); FMA4(a[0], av0.y, b1); FMA4(a[0], av0.z, b2); FMA4(a[0], av0.w, b3);
        FMA4(a[1], av1.x, b0); FMA4(a[1], av1.y, b1); FMA4(a[1], av1.z, b2); FMA4(a[1], av1.w, b3);
        FMA4(a[2], av2.x, b0); FMA4(a[2], av2.y, b1); FMA4(a[2], av2.z, b2); FMA4(a[2], av2.w, b3);
        FMA4(a[3], av3.x, b0); FMA4(a[3], av3.y, b1); FMA4(a[3], av3.z, b2); FMA4(a[3], av3.w, b3);
    }
}

// dot-style 4x4: a[r][c] += A[4ti+r][:] . B[4tj+c][:]
template<int SA, int SB>
__device__ __forceinline__ void mmdot(const float* __restrict__ A,
                                      const float* __restrict__ B,
                                      int ti, int tj, float a[4][4]) {
    #pragma unroll 4
    for (int m = 0; m < 64; m += 4) {
        float4 av[4], bv[4];
        #pragma unroll
        for (int r = 0; r < 4; ++r) av[r] = *(const float4*)&A[(4 * ti + r) * SA + m];
        #pragma unroll
        for (int c = 0; c < 4; ++c) bv[c] = *(const float4*)&B[(4 * tj + c) * SB + m];
        #pragma unroll
        for (int r = 0; r < 4; ++r)
            #pragma unroll
            for (int c = 0; c < 4; ++c)
                a[r][c] += av[r].x * bv[c].x + av[r].y * bv[c].y
                         + av[r].z * bv[c].z + av[r].w * bv[c].w;
    }
}

// Newton-Schulz: X <- X(2I - M X), X0 = alpha*I.
// First iteration is analytic: X1 = 2a*I - a^2*M (no matmul). sM stride SM.
template<int SM>
__device__ __forceinline__ void ns_invert(const float* sM, float* sX, float* sY,
                                          int iters, int ti, int tj,
                                          int tid, float alpha)
{
    const float a2 = alpha * alpha;
    for (int idx = tid; idx < 4096; idx += 256) {
        int i = idx >> 6, j = idx & 63;
        sX[i * LDP + j] = ((i == j) ? 2.f * alpha : 0.f) - a2 * sM[i * SM + j];
    }
    __syncthreads();
    for (int it = 1; it < iters; ++it) {
        float y[4][4] = {};
        mm64<SM, LDP>(sM, sX, ti, tj, y);          // Y = M*X
        #pragma unroll
        for (int r = 0; r < 4; ++r) {
            float4 v = {y[r][0], y[r][1], y[r][2], y[r][3]};
            *(float4*)&sY[(4 * ti + r) * 64 + 4 * tj] = v;
        }
        __syncthreads();
        float z[4][4] = {};
        mm64<LDP, 64>(sX, sY, ti, tj, z);           // Z = X*Y
        __syncthreads();
        #pragma unroll
        for (int r = 0; r < 4; ++r) {
            float4 xv = *(const float4*)&sX[(4 * ti + r) * LDP + 4 * tj];
            xv.x = 2.f * xv.x - z[r][0];
            xv.y = 2.f * xv.y - z[r][1];
            xv.z = 2.f * xv.z - z[r][2];
            xv.w = 2.f * xv.w - z[r][3];
            *(float4*)&sX[(4 * ti + r) * LDP + 4 * tj] = xv;
        }
        __syncthreads();
    }
}

// ---- device-scope producer/consumer handoff ------------------------------
__device__ __forceinline__ void wait_ge(int* flag, int target, int tid) {
    if (tid == 0) {
        while (__hip_atomic_load(flag, __ATOMIC_ACQUIRE, __HIP_MEMORY_SCOPE_AGENT) < target)
            __builtin_amdgcn_s_sleep(8);
    }
    __syncthreads();
    __threadfence();
}

__device__ __forceinline__ void signal_one(int* flag, int tid) {
    __syncthreads();
    __threadfence();
    if (tid == 0)
        (void)__hip_atomic_fetch_add(flag, 1, __ATOMIC_RELEASE, __HIP_MEMORY_SCOPE_AGENT);
}

// ---------------- single fused kernel, 251 co-resident blocks, 256 thr ----
// 0..239  : GEMM tiles (gx=bid&7 -> mat/m0, gy=bid>>3 over GYS k-strides),
//           register-double-buffered staging
// 240..243: G1 chunk ch = A_ch A_ch^T -> atomicAdd (waits flags[ch]==GYS)
// 244..247: FyAT chunk ch = Fy_ch A_ch^T -> atomicAdd (waits flags[ch],flags[4+ch])
// 248: b0 sy chain   249: b2 sx chain
// 250: solve = Frobenius + NS(G1) + Richardson (waits G1 chunks, then preps)
__global__ __launch_bounds__(256, 1) void fused_fmnet(
    const float* __restrict__ fx, const float* __restrict__ fy,
    const float* __restrict__ ex, const float* __restrict__ ey,
    const float* __restrict__ tx, const float* __restrict__ ty,
    const float* __restrict__ sx, const float* __restrict__ sy,
    float* __restrict__ ws, float* __restrict__ out)
{
    extern __shared__ __align__(16) float lds[];
    int* flags = (int*)(ws + WS_FLAGS);
    const int tid = threadIdx.x;
    const int ti = tid >> 4, tj = tid & 15;
    const int bid = blockIdx.x;

    if (bid < 240) {
        // ---------------- GEMM: 64x64 (mat,m0) tile, k-strided by gy ----
        float* sT = lds;            // sT[v][k] (transposed stage)
        float* sF = lds + 4352;     // sF[v][m]
        const int gx = bid & 7, gy = bid >> 3;
        const int mat = gx >> 2;
        const int m0 = (gx & 3) << 6;
        const float* __restrict__ T = mat ? ty : tx;
        const float* __restrict__ F = mat ? fy : fx;
        float* __restrict__ Out = ws + (mat ? WS_FY : WS_A);

        float4 tv[4], fv[4];
        int sc = gy;
        int vlen = 5000 - (sc << 6); if (vlen > 64) vlen = 64;
        // prologue: load chunk sc to regs, write to LDS
        #pragma unroll
        for (int w = 0; w < 4; ++w) {
            const int fidx = tid + (w << 8);
            const int row = fidx >> 4, q = fidx & 15, vv = q << 2;
            if (vv < vlen) tv[w] = *(const float4*)(T + (size_t)row * 5000 + (sc << 6) + vv);
            if (row < vlen) fv[w] = *(const float4*)(F + (size_t)((sc << 6) + row) * 256 + m0 + (q << 2));
        }
        #pragma unroll
        for (int w = 0; w < 4; ++w) {
            const int fidx = tid + (w << 8);
            const int row = fidx >> 4, q = fidx & 15, vv = q << 2;
            if (vv < vlen) {
                sT[(vv + 0) * LDP + row] = tv[w].x;
                sT[(vv + 1) * LDP + row] = tv[w].y;
                sT[(vv + 2) * LDP + row] = tv[w].z;
                sT[(vv + 3) * LDP + row] = tv[w].w;
            }
            if (row < vlen) *(float4*)&sF[row * LDP + (q << 2)] = fv[w];
        }
        __syncthreads();

        float acc[4][4] = {};
        for (;;) {
            const int nsc = sc + GYS;
            int nvlen = 5000 - (nsc << 6);
            if (nvlen > 64) nvlen = 64;
            if (nvlen > 0) {   // prefetch next chunk into regs (hides HBM/L2 latency)
                #pragma unroll
                for (int w = 0; w < 4; ++w) {
                    const int fidx = tid + (w << 8);
                    const int row = fidx >> 4, q = fidx & 15, vv = q << 2;
                    if (vv < nvlen) tv[w] = *(const float4*)(T + (size_t)row * 5000 + (nsc << 6) + vv);
                    if (row < nvlen) fv[w] = *(const float4*)(F + (size_t)((nsc << 6) + row) * 256 + m0 + (q << 2));
                }
            }
            #pragma unroll 4
            for (int v = 0; v < vlen; ++v) {
                float4 av = *(const float4*)&sT[v * LDP + 4 * ti];
                float4 bv = *(const float4*)&sF[v * LDP + 4 * tj];
                FMA4(acc[0], av.x, bv); FMA4(acc[1], av.y, bv);
                FMA4(acc[2], av.z, bv); FMA4(acc[3], av.w, bv);
            }
            if (nvlen <= 0) break;
            __syncthreads();
            #pragma unroll
            for (int w = 0; w < 4; ++w) {
                const int fidx = tid + (w << 8);
                const int row = fidx >> 4, q = fidx & 15, vv = q << 2;
                if (vv < nvlen) {
                    sT[(vv + 0) * LDP + row] = tv[w].x;
                    sT[(vv + 1) * LDP + row] = tv[w].y;
                    sT[(vv + 2) * LDP + row] = tv[w].z;
                    sT[(vv + 3) * LDP + row] = tv[w].w;
                }
                if (row < nvlen) *(float4*)&sF[row * LDP + (q << 2)] = fv[w];
            }
            __syncthreads();
            sc = nsc; vlen = nvlen;
        }
        #pragma unroll
        for (int r = 0; r < 4; ++r)
            #pragma unroll
            for (int c = 0; c < 4; ++c)
                atomicAdd(&Out[(4 * ti + r) * 256 + m0 + 4 * tj + c], acc[r][c]);
        __syncthreads();
        __threadfence();
        if (tid == 0)
            (void)__hip_atomic_fetch_add(&flags[gx], 1, __ATOMIC_RELEASE, __HIP_MEMORY_SCOPE_AGENT);
    } else if (bid < 244) {
        // ---------------- G1 chunk: A_ch A_ch^T -> atomicAdd WS_G1 ----
        const int ch = bid - 240;
        wait_ge(&flags[ch], GYS, tid);
        float* sA = lds;             // pad
        for (int idx = tid; idx < 1024; idx += 256) {
            int i = idx >> 4, m4 = (idx & 15) << 2;
            *(float4*)&sA[i * LDP + m4] =
                *(const float4*)&ws[WS_A + i * 256 + (ch << 6) + m4];
        }
        __syncthreads();
        float a[4][4] = {};
        mmdot<LDP, LDP>(sA, sA, ti, tj, a);
        #pragma unroll
        for (int r = 0; r < 4; ++r)
            #pragma unroll
            for (int c = 0; c < 4; ++c)
                atomicAdd(&ws[WS_G1 + (4 * ti + r) * 64 + 4 * tj + c], a[r][c]);
        __syncthreads();
        __threadfence();
        if (tid == 0)
            (void)__hip_atomic_fetch_add(&flags[8], 1, __ATOMIC_RELEASE, __HIP_MEMORY_SCOPE_AGENT);
    } else if (bid < 248) {
        // ---------------- FyAT chunk: Fy_ch A_ch^T -> atomicAdd WS_FYAT ----
        const int ch = bid - 244;
        wait_ge(&flags[ch], GYS, tid);
        wait_ge(&flags[4 + ch], GYS, tid);
        float* sFy = lds;            // pad
        float* sAx = lds + 4352;     // pad
        for (int idx = tid; idx < 1024; idx += 256) {
            int i = idx >> 4, m4 = (idx & 15) << 2;
            *(float4*)&sFy[i * LDP + m4] = *(const float4*)&ws[WS_FY + i * 256 + (ch << 6) + m4];
            *(float4*)&sAx[i * LDP + m4] = *(const float4*)&ws[WS_A  + i * 256 + (ch << 6) + m4];
        }
        __syncthreads();
        float a[4][4] = {};
        mmdot<LDP, LDP>(sFy, sAx, ti, tj, a);
        #pragma unroll
        for (int r = 0; r < 4; ++r)
            #pragma unroll
            for (int c = 0; c < 4; ++c)
                atomicAdd(&ws[WS_FYAT + (4 * ti + r) * 64 + 4 * tj + c], a[r][c]);
        signal_one(&flags[9], tid);
    } else if (bid == 248) {
        // ---------------- b0: sy chain (no deps) ----------------
        float* sSy = lds;            // pad: sy, later Hinv
        float* sXx = lds + 4352;     // pad: NS X -> Sinv
        float* sYy = lds + 8704;     // flat: NS tmp
        float* sH  = lds + 12800;    // flat: H1
        float* sV  = lds + 16896;    // ey
        for (int idx = tid; idx < 1024; idx += 256) {
            int i = idx >> 4, j4 = (idx & 15) << 2;
            *(float4*)&sSy[i * LDP + j4] = *(const float4*)&sy[i * 64 + j4];
        }
        if (tid < 64) sV[tid] = ey[tid];
        __syncthreads();
        // H1 = sy^T sy (column outer-product)
        {
            float h[4][4] = {};
            for (int k = 0; k < 64; ++k) {
                float4 av = *(const float4*)&sSy[k * LDP + 4 * ti];
                float4 bv = *(const float4*)&sSy[k * LDP + 4 * tj];
                FMA4(h[0], av.x, bv); FMA4(h[1], av.y, bv);
                FMA4(h[2], av.z, bv); FMA4(h[3], av.w, bv);
            }
            #pragma unroll
            for (int r = 0; r < 4; ++r) {
                float4 v = {h[r][0], h[r][1], h[r][2], h[r][3]};
                *(float4*)&sH[(4 * ti + r) * 64 + 4 * tj] = v;
            }
        }
        __syncthreads();
        ns_invert<LDP>(sSy, sXx, sYy, NS_SY, ti, tj, tid, 1.0f);   // Sinv
        // Hinv = Sinv Sinv^T -> overwrite sSy
        {
            float h[4][4] = {};
            mmdot<LDP, LDP>(sXx, sXx, ti, tj, h);
            __syncthreads();
            #pragma unroll
            for (int r = 0; r < 4; ++r) {
                float4 v = {h[r][0], h[r][1], h[r][2], h[r][3]};
                *(float4*)&sSy[(4 * ti + r) * LDP + 4 * tj] = v;
            }
        }
        __syncthreads();
        // C = Hinv * (D H1)
        {
            float a[4][4] = {};
            #pragma unroll 4
            for (int k = 0; k < 64; k += 4) {
                float4 av[4];
                #pragma unroll
                for (int r = 0; r < 4; ++r) av[r] = *(const float4*)&sSy[(4 * ti + r) * LDP + k];
                #pragma unroll
                for (int q = 0; q < 4; ++q) {
                    float e = sV[k + q];
                    float4 bv = *(const float4*)&sH[(k + q) * 64 + 4 * tj];
                    bv.x *= e; bv.y *= e; bv.z *= e; bv.w *= e;
                    float xq[4] = {av[0].x, av[1].x, av[2].x, av[3].x};
                    if (q == 1) { xq[0]=av[0].y; xq[1]=av[1].y; xq[2]=av[2].y; xq[3]=av[3].y; }
                    if (q == 2) { xq[0]=av[0].z; xq[1]=av[1].z; xq[2]=av[2].z; xq[3]=av[3].z; }
                    if (q == 3) { xq[0]=av[0].w; xq[1]=av[1].w; xq[2]=av[2].w; xq[3]=av[3].w; }
                    #pragma unroll
                    for (int r = 0; r < 4; ++r) FMA4(a[r], xq[r], bv);
                }
            }
            #pragma unroll
            for (int r = 0; r < 4; ++r) {
                float4 v = {a[r][0], a[r][1], a[r][2], a[r][3]};
                *(float4*)&ws[WS_C + (4 * ti + r) * 64 + 4 * tj] = v;
            }
        }
        signal_one(&flags[9], tid);
    } else if (bid == 249) {
        // ---------------- b2: sx chain (no deps) ----------------
        float* sM = lds;             // pad: sx
        float* sX = lds + 4352;      // pad: P
        float* sY = lds + 8704;      // flat
        float* sV = lds + 12800;     // ex
        for (int idx = tid; idx < 1024; idx += 256) {
            int i = idx >> 4, j4 = (idx & 15) << 2;
            *(float4*)&sM[i * LDP + j4] = *(const float4*)&sx[i * 64 + j4];
        }
        if (tid < 64) sV[tid] = ex[tid];
        __syncthreads();
        ns_invert<LDP>(sM, sX, sY, NS_SX, ti, tj, tid, 1.0f);
        float aR2[4][4] = {}, aR4[4][4] = {}, aT1[4][4] = {};
        for (int k = 0; k < 64; ++k) {
            float e = sV[k], e2 = e * e;
            float4 av = *(const float4*)&sX[k * LDP + 4 * ti];
            float4 bv = *(const float4*)&sX[k * LDP + 4 * tj];
            float avv[4] = {av.x, av.y, av.z, av.w};
            #pragma unroll
            for (int r = 0; r < 4; ++r) {
                FMA4(aR4[r], avv[r], bv);
                float ea = e * avv[r];
                FMA4(aR2[r], ea, bv);
                float e2a = e2 * avv[r];
                FMA4(aT1[r], e2a, bv);
            }
        }
        #pragma unroll
        for (int r = 0; r < 4; ++r) {
            int o = (4 * ti + r) * 64 + 4 * tj;
            float4 v2 = {aR2[r][0], aR2[r][1], aR2[r][2], aR2[r][3]};
            float4 v4 = {aR4[r][0], aR4[r][1], aR4[r][2], aR4[r][3]};
            float4 v1 = {aT1[r][0], aT1[r][1], aT1[r][2], aT1[r][3]};
            *(float4*)&ws[WS_R2 + o] = v2;
            *(float4*)&ws[WS_R4 + o] = v4;
            *(float4*)&ws[WS_T1 + o] = v1;
        }
        signal_one(&flags[9], tid);
    } else {
        // ---------------- solve: Frobenius + NS(G1) + Richardson ----------
        float* cM1   = lds;              // flat (G1 during NS, then M1)
        float* cR2   = lds + 4096;      // flat
        float* cR4   = lds + 8192;      // flat
        float* cGinv = lds + 12288;     // flat
        float* sE    = lds + 16384;     // flat (NS tmp Y, then E2)
        float* sX    = lds + 20480;     // pad  (NS X, then Richardson X)
        float* cC    = lds + 24832;     // pad
        float* sW    = lds + 29184;     // pad  (Frobenius scratch, then W)

        wait_ge(&flags[8], 4, tid);      // G1 complete
        for (int idx = tid; idx < 1024; idx += 256) {
            int i = idx >> 4, j4 = (idx & 15) << 2;
            *(float4*)&cM1[i * 64 + j4] = *(const float4*)&ws[WS_G1 + i * 64 + j4];
        }
        __syncthreads();
        // Frobenius-optimal alpha = tr(G1)/||G1||_F^2
        if (tid < 64) {
            float s = 0.f;
            for (int j4 = 0; j4 < 64; j4 += 4) {
                float4 v = *(const float4*)&cM1[tid * 64 + j4];
                s += v.x * v.x + v.y * v.y + v.z * v.z + v.w * v.w;
            }
            sW[tid] = s;
            sW[64 + tid] = cM1[tid * 64 + tid];
        }
        __syncthreads();
        float f2 = 0.f, tr = 0.f;
        for (int i = 0; i < 64; ++i) { f2 += sW[i]; tr += sW[64 + i]; }
        ns_invert<64>(cM1, sX, sE, NS_G, ti, tj, tid, tr / f2);
        // copy Ginv (pad sX) -> cGinv (flat)
        for (int idx = tid; idx < 1024; idx += 256) {
            int i = idx >> 4, j4 = (idx & 15) << 2;
            *(float4*)&cGinv[i * 64 + j4] = *(const float4*)&sX[i * LDP + j4];
        }
        wait_ge(&flags[9], 6, tid);      // b0, b2, 4 FyAT chunks done
        // cM1 = G1 + lambda*T1 (in place); stage cR2/cR4/cC
        for (int idx = tid; idx < 1024; idx += 256) {
            int i = idx >> 4, j4 = (idx & 15) << 2;
            int o = i * 64 + j4;
            float4 gv = *(const float4*)&cM1[o];
            float4 t = *(const float4*)&ws[WS_T1 + o];
            gv.x = fmaf(LMBDA, t.x, gv.x); gv.y = fmaf(LMBDA, t.y, gv.y);
            gv.z = fmaf(LMBDA, t.z, gv.z); gv.w = fmaf(LMBDA, t.w, gv.w);
            *(float4*)&cM1[o] = gv;
            *(float4*)&cR2[o] = *(const float4*)&ws[WS_R2 + o];
            *(float4*)&cR4[o] = *(const float4*)&ws[WS_R4 + o];
            *(float4*)&cC[i * LDP + j4] = *(const float4*)&ws[WS_C + o];
        }
        float4 eyv = *(const float4*)&ey[4 * ti];
        float eyr[4] = {eyv.x, eyv.y, eyv.z, eyv.w};
        float leyr[4];
        #pragma unroll
        for (int r = 0; r < 4; ++r) leyr[r] = LMBDA * eyr[r];

        float fyr[4][4], xreg[4][4];
        #pragma unroll
        for (int r = 0; r < 4; ++r) {
            float4 v = *(const float4*)&ws[WS_FYAT + (4 * ti + r) * 64 + 4 * tj];
            fyr[r][0] = v.x; fyr[r][1] = v.y; fyr[r][2] = v.z; fyr[r][3] = v.w;
            float4 z = {0.f, 0.f, 0.f, 0.f};
            *(float4*)&sX[(4 * ti + r) * LDP + 4 * tj] = z;
            #pragma unroll
            for (int c = 0; c < 4; ++c) xreg[r][c] = 0.f;
        }
        __syncthreads();

        float E1[4][4];
        for (int it = 0; it < OUTER; ++it) {
            // grp1: Sm=X*M1, S2=X*R2, S4=X*R4 (shared A-reads)
            {
                float Sm[4][4] = {}, S2[4][4] = {}, S4[4][4] = {};
                #pragma unroll 2
                for (int k = 0; k < 64; k += 4) {
                    float4 av[4];
                    #pragma unroll
                    for (int r = 0; r < 4; ++r)
                        av[r] = *(const float4*)&sX[(4 * ti + r) * LDP + k];
                    #pragma unroll
                    for (int q = 0; q < 4; ++q) {
                        float4 mv = *(const float4*)&cM1[(k + q) * 64 + 4 * tj];
                        float4 qv = *(const float4*)&cR2[(k + q) * 64 + 4 * tj];
                        float4 rv = *(const float4*)&cR4[(k + q) * 64 + 4 * tj];
                        float xq[4] = {av[0].x, av[1].x, av[2].x, av[3].x};
                        if (q == 1) { xq[0]=av[0].y; xq[1]=av[1].y; xq[2]=av[2].y; xq[3]=av[3].y; }
                        if (q == 2) { xq[0]=av[0].z; xq[1]=av[1].z; xq[2]=av[2].z; xq[3]=av[3].z; }
                        if (q == 3) { xq[0]=av[0].w; xq[1]=av[1].w; xq[2]=av[2].w; xq[3]=av[3].w; }
                        #pragma unroll
                        for (int r = 0; r < 4; ++r) {
                            FMA4(Sm[r], xq[r], mv);
                            FMA4(S2[r], xq[r], qv);
                            FMA4(S4[r], xq[r], rv);
                        }
                    }
                }
                #pragma unroll
                for (int r = 0; r < 4; ++r) {
                    float4 e2;
                    e2.x = LMBDA * fmaf(eyr[r], S4[r][0], -S2[r][0]);
                    e2.y = LMBDA * fmaf(eyr[r], S4[r][1], -S2[r][1]);
                    e2.z = LMBDA * fmaf(eyr[r], S4[r][2], -S2[r][2]);
                    e2.w = LMBDA * fmaf(eyr[r], S4[r][3], -S2[r][3]);
                    *(float4*)&sE[(4 * ti + r) * 64 + 4 * tj] = e2;
                    #pragma unroll
                    for (int c = 0; c < 4; ++c)
                        E1[r][c] = fmaf(-leyr[r], S2[r][c], Sm[r][c]);
                }
            }
            __syncthreads();
            // grp2: Z = C*E2 ; W = FyAT - E1 - Z
            {
                float Z[4][4] = {};
                mm64<LDP, 64>(cC, sE, ti, tj, Z);
                #pragma unroll
                for (int r = 0; r < 4; ++r) {
                    float4 w;
                    w.x = fyr[r][0] - E1[r][0] - Z[r][0];
                    w.y = fyr[r][1] - E1[r][1] - Z[r][1];
                    w.z = fyr[r][2] - E1[r][2] - Z[r][2];
                    w.w = fyr[r][3] - E1[r][3] - Z[r][3];
                    *(float4*)&sW[(4 * ti + r) * LDP + 4 * tj] = w;
                }
            }
            __syncthreads();
            // grp3: dX = W*Ginv ; X += dX
            {
                float dX[4][4] = {};
                mm64<LDP, 64>(sW, cGinv, ti, tj, dX);
                #pragma unroll
                for (int r = 0; r < 4; ++r) {
                    float4 v;
                    #pragma unroll
                    for (int c = 0; c < 4; ++c) xreg[r][c] += dX[r][c];
                    v.x = xreg[r][0]; v.y = xreg[r][1]; v.z = xreg[r][2]; v.w = xreg[r][3];
                    *(float4*)&sX[(4 * ti + r) * LDP + 4 * tj] = v;
                    if (it == OUTER - 1)
                        *(float4*)&out[(4 * ti + r) * 64 + 4 * tj] = v;
                }
            }
            if (it == OUTER - 1) break;
            __syncthreads();
        }
    }
}

extern "C" void kernel_launch(void* const* d_in, const int* in_sizes, int n_in,
                              void* d_out, int out_size, void* d_ws, size_t ws_size,
                              hipStream_t stream) {
    (void)in_sizes; (void)n_in; (void)out_size; (void)ws_size;
    const float* fx = (const float*)d_in[0];
    const float* fy = (const float*)d_in[1];
    const float* ex = (const float*)d_in[2];
    const float* ey = (const float*)d_in[3];
    const float* tx = (const float*)d_in[4];
    const float* ty = (const float*)d_in[5];
    const float* sx = (const float*)d_in[6];
    const float* sy = (const float*)d_in[7];
    float* ws = (float*)d_ws;
    float* out = (float*)d_out;

    (void)hipFuncSetAttribute((const void*)fused_fmnet,
                              hipFuncAttributeMaxDynamicSharedMemorySize, 134144);

    // zero A/Fy/G1/FyAT accumulators + flags
    (void)hipMemsetAsync(d_ws, 0, (size_t)(WS_T1) * sizeof(float), stream);
    (void)hipMemsetAsync((char*)d_ws + (size_t)WS_FLAGS * sizeof(float), 0, 64, stream);
    fused_fmnet<<<251, 256, 134144, stream>>>(fx, fy, ex, ey, tx, ty, sx, sy, ws, out);
}

// Round 6
// 170.581 us; speedup vs baseline: 1.1453x; 1.0676x over previous
//
#include <hip/hip_runtime.h>

#define LMBDA 0.001f
#define NS_SY 4     // NS iters for inv(sy) (first iter analytic)
#define NS_SX 5     // NS iters for inv(sx) (first iter analytic)
#define OUTER_FULL 2 // full Richardson iters after the free X1 = FyAT*Ginv (== old OUTER=3)
#define LDP 68      // padded stride
#define GYS 30      // gy k-stride count (240 gemm blocks)

// workspace layout (float offsets) — [0, 40960) is memset to 0 each launch
#define WS_A    0        // 64*256 (atomic-accumulated)
#define WS_FY   16384    // 64*256 (atomic-accumulated)
#define WS_G1   32768    // 64*64  (atomic-accumulated by 4 chunk blocks)
#define WS_FYAT 36864    // 64*64  (atomic-accumulated by 4 chunk blocks)
#define WS_T1   40960
#define WS_R2   45056
#define WS_R4   49152
#define WS_C    53248
#define WS_FLAGS 57344   // ints: [0..7] per-gx gemm cnt (GYS) [8] G1 chunks (4) [9] preps (6)

#define FMA4(ar, xs, b) { ar[0]=fmaf((xs),(b).x,ar[0]); ar[1]=fmaf((xs),(b).y,ar[1]); \
                          ar[2]=fmaf((xs),(b).z,ar[2]); ar[3]=fmaf((xs),(b).w,ar[3]); }
#define COMP(v,q) ((q)==0?(v).x:((q)==1?(v).y:((q)==2?(v).z:(v).w)))

// C-tile += A[4ti..][:] * B[:][4tj..]; all f4 (b128) LDS reads
template<int SA, int SB>
__device__ __forceinline__ void mm64(const float* __restrict__ A,
                                     const float* __restrict__ B,
                                     int ti, int tj, float a[4][4]) {
    #pragma unroll 4
    for (int k = 0; k < 64; k += 4) {
        float4 av0 = *(const float4*)&A[(4 * ti + 0) * SA + k];
        float4 av1 = *(const float4*)&A[(4 * ti + 1) * SA + k];
        float4 av2 = *(const float4*)&A[(4 * ti + 2) * SA + k];
        float4 av3 = *(const float4*)&A[(4 * ti + 3) * SA + k];
        float4 b0 = *(const float4*)&B[(k + 0) * SB + 4 * tj];
        float4 b1 = *(const float4*)&B[(k + 1) * SB + 4 * tj];
        float4 b2 = *(const float4*)&B[(k + 2) * SB + 4 * tj];
        float4 b3 = *(const float4*)&B[(k + 3) * SB + 4 * tj];
        FMA4(a[0], av0.x, b0); FMA4(a[0], av0.y, b1); FMA4(a[0], av0.z, b2); FMA4(a[0], av0.w, b3);
        FMA4(a[1], av1.x, b0); FMA4(a[1], av1.y, b1); FMA4(a[1], av1.z, b2); FMA4(a[1], av1.w, b3);
        FMA4(a[2], av2.x, b0); FMA4(a[2], av2.y, b1); FMA4(a[2], av2.z, b2); FMA4(a[2], av2.w, b3);
        FMA4(a[3], av3.x, b0); FMA4(a[3], av3.y, b1); FMA4(a[3], av3.z, b2); FMA4(a[3], av3.w, b3);
    }
}

// dot-style 4x4: a[r][c] += A[4ti+r][:] . B[4tj+c][:]
template<int SA, int SB>
__device__ __forceinline__ void mmdot(const float* __restrict__ A,
                                      const float* __restrict__ B,
                                      int ti, int tj, float a[4][4]) {
    #pragma unroll 4
    for (int m = 0; m < 64; m += 4) {
        float4 av[4], bv[4];
        #pragma unroll
        for (int r = 0; r < 4; ++r) av[r] = *(const float4*)&A[(4 * ti + r) * SA + m];
        #pragma unroll
        for (int c = 0; c < 4; ++c) bv[c] = *(const float4*)&B[(4 * tj + c) * SB + m];
        #pragma unroll
        for (int r = 0; r < 4; ++r)
            #pragma unroll
            for (int c = 0; c < 4; ++c)
                a[r][c] += av[r].x * bv[c].x + av[r].y * bv[c].y
                         + av[r].z * bv[c].z + av[r].w * bv[c].w;
    }
}

// Newton-Schulz (classic, for b0/b2): X <- X(2I - M X), X0 = alpha*I.
// First iteration analytic: X1 = 2a*I - a^2*M. sM stride SM; sX pad; sY flat
template<int SM>
__device__ __forceinline__ void ns_invert(const float* sM, float* sX, float* sY,
                                          int iters, int ti, int tj,
                                          int tid, float alpha)
{
    const float a2 = alpha * alpha;
    for (int idx = tid; idx < 4096; idx += 256) {
        int i = idx >> 6, j = idx & 63;
        sX[i * LDP + j] = ((i == j) ? 2.f * alpha : 0.f) - a2 * sM[i * SM + j];
    }
    __syncthreads();
    for (int it = 1; it < iters; ++it) {
        float y[4][4] = {};
        mm64<SM, LDP>(sM, sX, ti, tj, y);          // Y = M*X
        #pragma unroll
        for (int r = 0; r < 4; ++r) {
            float4 v = {y[r][0], y[r][1], y[r][2], y[r][3]};
            *(float4*)&sY[(4 * ti + r) * 64 + 4 * tj] = v;
        }
        __syncthreads();
        float z[4][4] = {};
        mm64<LDP, 64>(sX, sY, ti, tj, z);           // Z = X*Y
        __syncthreads();
        #pragma unroll
        for (int r = 0; r < 4; ++r) {
            float4 xv = *(const float4*)&sX[(4 * ti + r) * LDP + 4 * tj];
            xv.x = 2.f * xv.x - z[r][0];
            xv.y = 2.f * xv.y - z[r][1];
            xv.z = 2.f * xv.z - z[r][2];
            xv.w = 2.f * xv.w - z[r][3];
            *(float4*)&sX[(4 * ti + r) * LDP + 4 * tj] = xv;
        }
        __syncthreads();
    }
}

// Residual-form NS fused pass: Xd = Xs + Xs*Rs ; (DOR) Rd = Rs*Rs.
// Shares the B-operand (Rs) between both products: 12 LDS reads per 4-k
// instead of 16 -> 1.5 mm64-equiv for two matmuls. Ends with barrier.
template<bool DOR>
__device__ __forceinline__ void ns_pass(const float* Xs, const float* Rs,
                                        float* Xd, float* Rd, int ti, int tj)
{
    float xr[4][4] = {}, rr[4][4] = {};
    #pragma unroll 4
    for (int k = 0; k < 64; k += 4) {
        float4 xa[4], ra[4];
        #pragma unroll
        for (int r = 0; r < 4; ++r) {
            xa[r] = *(const float4*)&Xs[(4 * ti + r) * LDP + k];
            if (DOR) ra[r] = *(const float4*)&Rs[(4 * ti + r) * LDP + k];
        }
        #pragma unroll
        for (int q = 0; q < 4; ++q) {
            float4 bv = *(const float4*)&Rs[(k + q) * LDP + 4 * tj];
            #pragma unroll
            for (int r = 0; r < 4; ++r) {
                FMA4(xr[r], COMP(xa[r], q), bv);
                if (DOR) FMA4(rr[r], COMP(ra[r], q), bv);
            }
        }
    }
    #pragma unroll
    for (int r = 0; r < 4; ++r) {
        float4 xo = *(const float4*)&Xs[(4 * ti + r) * LDP + 4 * tj];
        float4 xn = {xo.x + xr[r][0], xo.y + xr[r][1],
                     xo.z + xr[r][2], xo.w + xr[r][3]};
        *(float4*)&Xd[(4 * ti + r) * LDP + 4 * tj] = xn;
        if (DOR) {
            float4 rv = {rr[r][0], rr[r][1], rr[r][2], rr[r][3]};
            *(float4*)&Rd[(4 * ti + r) * LDP + 4 * tj] = rv;
        }
    }
    __syncthreads();
}

// ---- device-scope producer/consumer handoff ------------------------------
__device__ __forceinline__ void wait_ge(int* flag, int target, int tid) {
    if (tid == 0) {
        while (__hip_atomic_load(flag, __ATOMIC_ACQUIRE, __HIP_MEMORY_SCOPE_AGENT) < target)
            __builtin_amdgcn_s_sleep(8);
    }
    __syncthreads();
    __threadfence();
}

__device__ __forceinline__ void signal_one(int* flag, int tid) {
    __syncthreads();
    __threadfence();
    if (tid == 0)
        (void)__hip_atomic_fetch_add(flag, 1, __ATOMIC_RELEASE, __HIP_MEMORY_SCOPE_AGENT);
}

// ---------------- single fused kernel, 251 co-resident blocks, 256 thr ----
// 0..239  : GEMM tiles (gx=bid&7 -> mat/m0, gy=bid>>3 over GYS k-strides)
// 240..243: G1 chunk ch = A_ch A_ch^T -> atomicAdd (waits flags[ch]==GYS)
// 244..247: FyAT chunk ch -> atomicAdd (waits flags[ch],flags[4+ch])
// 248: b0 sy chain   249: b2 sx chain
// 250: solve = Frobenius + residual-NS(G1) + free-X1 + 2 full Richardson
__global__ __launch_bounds__(256, 1) void fused_fmnet(
    const float* __restrict__ fx, const float* __restrict__ fy,
    const float* __restrict__ ex, const float* __restrict__ ey,
    const float* __restrict__ tx, const float* __restrict__ ty,
    const float* __restrict__ sx, const float* __restrict__ sy,
    float* __restrict__ ws, float* __restrict__ out)
{
    extern __shared__ __align__(16) float lds[];
    int* flags = (int*)(ws + WS_FLAGS);
    const int tid = threadIdx.x;
    const int ti = tid >> 4, tj = tid & 15;
    const int bid = blockIdx.x;

    if (bid < 240) {
        // ---------------- GEMM: 64x64 (mat,m0) tile, k-strided by gy ----
        float* sT = lds;            // sT[v][k] (transposed stage)
        float* sF = lds + 4352;     // sF[v][m]
        const int gx = bid & 7, gy = bid >> 3;
        const int mat = gx >> 2;
        const int m0 = (gx & 3) << 6;
        const float* __restrict__ T = mat ? ty : tx;
        const float* __restrict__ F = mat ? fy : fx;
        float* __restrict__ Out = ws + (mat ? WS_FY : WS_A);

        float4 tv[4], fv[4];
        int sc = gy;
        int vlen = 5000 - (sc << 6); if (vlen > 64) vlen = 64;
        #pragma unroll
        for (int w = 0; w < 4; ++w) {
            const int fidx = tid + (w << 8);
            const int row = fidx >> 4, q = fidx & 15, vv = q << 2;
            if (vv < vlen) tv[w] = *(const float4*)(T + (size_t)row * 5000 + (sc << 6) + vv);
            if (row < vlen) fv[w] = *(const float4*)(F + (size_t)((sc << 6) + row) * 256 + m0 + (q << 2));
        }
        #pragma unroll
        for (int w = 0; w < 4; ++w) {
            const int fidx = tid + (w << 8);
            const int row = fidx >> 4, q = fidx & 15, vv = q << 2;
            if (vv < vlen) {
                sT[(vv + 0) * LDP + row] = tv[w].x;
                sT[(vv + 1) * LDP + row] = tv[w].y;
                sT[(vv + 2) * LDP + row] = tv[w].z;
                sT[(vv + 3) * LDP + row] = tv[w].w;
            }
            if (row < vlen) *(float4*)&sF[row * LDP + (q << 2)] = fv[w];
        }
        __syncthreads();

        float acc[4][4] = {};
        for (;;) {
            const int nsc = sc + GYS;
            int nvlen = 5000 - (nsc << 6);
            if (nvlen > 64) nvlen = 64;
            if (nvlen > 0) {   // prefetch next chunk into regs
                #pragma unroll
                for (int w = 0; w < 4; ++w) {
                    const int fidx = tid + (w << 8);
                    const int row = fidx >> 4, q = fidx & 15, vv = q << 2;
                    if (vv < nvlen) tv[w] = *(const float4*)(T + (size_t)row * 5000 + (nsc << 6) + vv);
                    if (row < nvlen) fv[w] = *(const float4*)(F + (size_t)((nsc << 6) + row) * 256 + m0 + (q << 2));
                }
            }
            #pragma unroll 4
            for (int v = 0; v < vlen; ++v) {
                float4 av = *(const float4*)&sT[v * LDP + 4 * ti];
                float4 bv = *(const float4*)&sF[v * LDP + 4 * tj];
                FMA4(acc[0], av.x, bv); FMA4(acc[1], av.y, bv);
                FMA4(acc[2], av.z, bv); FMA4(acc[3], av.w, bv);
            }
            if (nvlen <= 0) break;
            __syncthreads();
            #pragma unroll
            for (int w = 0; w < 4; ++w) {
                const int fidx = tid + (w << 8);
                const int row = fidx >> 4, q = fidx & 15, vv = q << 2;
                if (vv < nvlen) {
                    sT[(vv + 0) * LDP + row] = tv[w].x;
                    sT[(vv + 1) * LDP + row] = tv[w].y;
                    sT[(vv + 2) * LDP + row] = tv[w].z;
                    sT[(vv + 3) * LDP + row] = tv[w].w;
                }
                if (row < nvlen) *(float4*)&sF[row * LDP + (q << 2)] = fv[w];
            }
            __syncthreads();
            sc = nsc; vlen = nvlen;
        }
        #pragma unroll
        for (int r = 0; r < 4; ++r)
            #pragma unroll
            for (int c = 0; c < 4; ++c)
                atomicAdd(&Out[(4 * ti + r) * 256 + m0 + 4 * tj + c], acc[r][c]);
        __syncthreads();
        __threadfence();
        if (tid == 0)
            (void)__hip_atomic_fetch_add(&flags[gx], 1, __ATOMIC_RELEASE, __HIP_MEMORY_SCOPE_AGENT);
    } else if (bid < 244) {
        // ---------------- G1 chunk: A_ch A_ch^T -> atomicAdd WS_G1 ----
        const int ch = bid - 240;
        wait_ge(&flags[ch], GYS, tid);
        float* sA = lds;             // pad
        for (int idx = tid; idx < 1024; idx += 256) {
            int i = idx >> 4, m4 = (idx & 15) << 2;
            *(float4*)&sA[i * LDP + m4] =
                *(const float4*)&ws[WS_A + i * 256 + (ch << 6) + m4];
        }
        __syncthreads();
        float a[4][4] = {};
        mmdot<LDP, LDP>(sA, sA, ti, tj, a);
        #pragma unroll
        for (int r = 0; r < 4; ++r)
            #pragma unroll
            for (int c = 0; c < 4; ++c)
                atomicAdd(&ws[WS_G1 + (4 * ti + r) * 64 + 4 * tj + c], a[r][c]);
        __syncthreads();
        __threadfence();
        if (tid == 0)
            (void)__hip_atomic_fetch_add(&flags[8], 1, __ATOMIC_RELEASE, __HIP_MEMORY_SCOPE_AGENT);
    } else if (bid < 248) {
        // ---------------- FyAT chunk: Fy_ch A_ch^T -> atomicAdd WS_FYAT ----
        const int ch = bid - 244;
        wait_ge(&flags[ch], GYS, tid);
        wait_ge(&flags[4 + ch], GYS, tid);
        float* sFy = lds;            // pad
        float* sAx = lds + 4352;     // pad
        for (int idx = tid; idx < 1024; idx += 256) {
            int i = idx >> 4, m4 = (idx & 15) << 2;
            *(float4*)&sFy[i * LDP + m4] = *(const float4*)&ws[WS_FY + i * 256 + (ch << 6) + m4];
            *(float4*)&sAx[i * LDP + m4] = *(const float4*)&ws[WS_A  + i * 256 + (ch << 6) + m4];
        }
        __syncthreads();
        float a[4][4] = {};
        mmdot<LDP, LDP>(sFy, sAx, ti, tj, a);
        #pragma unroll
        for (int r = 0; r < 4; ++r)
            #pragma unroll
            for (int c = 0; c < 4; ++c)
                atomicAdd(&ws[WS_FYAT + (4 * ti + r) * 64 + 4 * tj + c], a[r][c]);
        signal_one(&flags[9], tid);
    } else if (bid == 248) {
        // ---------------- b0: sy chain (no deps) ----------------
        float* sSy = lds;            // pad: sy, later Hinv
        float* sXx = lds + 4352;     // pad: NS X -> Sinv
        float* sYy = lds + 8704;     // flat: NS tmp
        float* sH  = lds + 12800;    // flat: H1
        float* sV  = lds + 16896;    // ey
        for (int idx = tid; idx < 1024; idx += 256) {
            int i = idx >> 4, j4 = (idx & 15) << 2;
            *(float4*)&sSy[i * LDP + j4] = *(const float4*)&sy[i * 64 + j4];
        }
        if (tid < 64) sV[tid] = ey[tid];
        __syncthreads();
        // H1 = sy^T sy (column outer-product)
        {
            float h[4][4] = {};
            for (int k = 0; k < 64; ++k) {
                float4 av = *(const float4*)&sSy[k * LDP + 4 * ti];
                float4 bv = *(const float4*)&sSy[k * LDP + 4 * tj];
                FMA4(h[0], av.x, bv); FMA4(h[1], av.y, bv);
                FMA4(h[2], av.z, bv); FMA4(h[3], av.w, bv);
            }
            #pragma unroll
            for (int r = 0; r < 4; ++r) {
                float4 v = {h[r][0], h[r][1], h[r][2], h[r][3]};
                *(float4*)&sH[(4 * ti + r) * 64 + 4 * tj] = v;
            }
        }
        __syncthreads();
        ns_invert<LDP>(sSy, sXx, sYy, NS_SY, ti, tj, tid, 1.0f);   // Sinv
        // Hinv = Sinv Sinv^T -> overwrite sSy
        {
            float h[4][4] = {};
            mmdot<LDP, LDP>(sXx, sXx, ti, tj, h);
            __syncthreads();
            #pragma unroll
            for (int r = 0; r < 4; ++r) {
                float4 v = {h[r][0], h[r][1], h[r][2], h[r][3]};
                *(float4*)&sSy[(4 * ti + r) * LDP + 4 * tj] = v;
            }
        }
        __syncthreads();
        // C = Hinv * (D H1)
        {
            float a[4][4] = {};
            #pragma unroll 4
            for (int k = 0; k < 64; k += 4) {
                float4 av[4];
                #pragma unroll
                for (int r = 0; r < 4; ++r) av[r] = *(const float4*)&sSy[(4 * ti + r) * LDP + k];
                #pragma unroll
                for (int q = 0; q < 4; ++q) {
                    float e = sV[k + q];
                    float4 bv = *(const float4*)&sH[(k + q) * 64 + 4 * tj];
                    bv.x *= e; bv.y *= e; bv.z *= e; bv.w *= e;
                    #pragma unroll
                    for (int r = 0; r < 4; ++r) FMA4(a[r], COMP(av[r], q), bv);
                }
            }
            #pragma unroll
            for (int r = 0; r < 4; ++r) {
                float4 v = {a[r][0], a[r][1], a[r][2], a[r][3]};
                *(float4*)&ws[WS_C + (4 * ti + r) * 64 + 4 * tj] = v;
            }
        }
        signal_one(&flags[9], tid);
    } else if (bid == 249) {
        // ---------------- b2: sx chain (no deps) ----------------
        float* sM = lds;             // pad: sx
        float* sX = lds + 4352;      // pad: P
        float* sY = lds + 8704;      // flat
        float* sV = lds + 12800;     // ex
        for (int idx = tid; idx < 1024; idx += 256) {
            int i = idx >> 4, j4 = (idx & 15) << 2;
            *(float4*)&sM[i * LDP + j4] = *(const float4*)&sx[i * 64 + j4];
        }
        if (tid < 64) sV[tid] = ex[tid];
        __syncthreads();
        ns_invert<LDP>(sM, sX, sY, NS_SX, ti, tj, tid, 1.0f);
        float aR2[4][4] = {}, aR4[4][4] = {}, aT1[4][4] = {};
        for (int k = 0; k < 64; ++k) {
            float e = sV[k], e2 = e * e;
            float4 av = *(const float4*)&sX[k * LDP + 4 * ti];
            float4 bv = *(const float4*)&sX[k * LDP + 4 * tj];
            float avv[4] = {av.x, av.y, av.z, av.w};
            #pragma unroll
            for (int r = 0; r < 4; ++r) {
                FMA4(aR4[r], avv[r], bv);
                float ea = e * avv[r];
                FMA4(aR2[r], ea, bv);
                float e2a = e2 * avv[r];
                FMA4(aT1[r], e2a, bv);
            }
        }
        #pragma unroll
        for (int r = 0; r < 4; ++r) {
            int o = (4 * ti + r) * 64 + 4 * tj;
            float4 v2 = {aR2[r][0], aR2[r][1], aR2[r][2], aR2[r][3]};
            float4 v4 = {aR4[r][0], aR4[r][1], aR4[r][2], aR4[r][3]};
            float4 v1 = {aT1[r][0], aT1[r][1], aT1[r][2], aT1[r][3]};
            *(float4*)&ws[WS_R2 + o] = v2;
            *(float4*)&ws[WS_R4 + o] = v4;
            *(float4*)&ws[WS_T1 + o] = v1;
        }
        signal_one(&flags[9], tid);
    } else {
        // ---------------- solve: residual-NS(G1) + free-X1 + Richardson ----
        // LDS plan (floats):
        //   sM  0      flat 4096 : G1 -> M1 (in place)
        //   P1  4096   pad  4352 : Frob scratch / R1,R3 / FyAT-stage,E2,W
        //   P2  8448   pad  4352 : R0,R2,R4 / C
        //   P3  12800  pad  4352 : X1,X3,X5=Ginv (in place)
        //   P4  17152  pad  4352 : X2,X4 / Richardson X
        //   cR2 21504  flat 4096
        //   cR4 25600  flat 4096    (peak 29696 floats = 118.8 KB)
        float* sM  = lds;
        float* P1  = lds + 4096;
        float* P2  = lds + 8448;
        float* P3  = lds + 12800;
        float* P4  = lds + 17152;
        float* cR2 = lds + 21504;
        float* cR4 = lds + 25600;

        wait_ge(&flags[8], 4, tid);      // G1 complete
        for (int idx = tid; idx < 1024; idx += 256) {
            int i = idx >> 4, j4 = (idx & 15) << 2;
            *(float4*)&sM[i * 64 + j4] = *(const float4*)&ws[WS_G1 + i * 64 + j4];
        }
        __syncthreads();
        // Frobenius-optimal alpha = tr(G1)/||G1||_F^2 (scratch in P1)
        if (tid < 64) {
            float s = 0.f;
            for (int j4 = 0; j4 < 64; j4 += 4) {
                float4 v = *(const float4*)&sM[tid * 64 + j4];
                s += v.x * v.x + v.y * v.y + v.z * v.z + v.w * v.w;
            }
            P1[tid] = s;
            P1[64 + tid] = sM[tid * 64 + tid];
        }
        __syncthreads();
        float f2 = 0.f, tr = 0.f;
        for (int i = 0; i < 64; ++i) { f2 += P1[i]; tr += P1[64 + i]; }
        const float alpha = tr / f2, a2 = alpha * alpha;
        // analytic: X1 = 2a I - a^2 G -> P3 ; R0 = I - a G -> P2
        for (int idx = tid; idx < 4096; idx += 256) {
            int i = idx >> 6, j = idx & 63;
            float g = sM[i * 64 + j];
            float d = (i == j) ? 1.f : 0.f;
            P3[i * LDP + j] = 2.f * alpha * d - a2 * g;
            P2[i * LDP + j] = d - alpha * g;
        }
        __syncthreads();
        // R1 = R0^2 -> P1
        {
            float z[4][4] = {};
            mm64<LDP, LDP>(P2, P2, ti, tj, z);
            #pragma unroll
            for (int r = 0; r < 4; ++r) {
                float4 v = {z[r][0], z[r][1], z[r][2], z[r][3]};
                *(float4*)&P1[(4 * ti + r) * LDP + 4 * tj] = v;
            }
            __syncthreads();
        }
        // fused residual-NS: X_{k+1}=X_k(I+R_k), R_{k+1}=R_k^2 (last skips R)
        ns_pass<true >(P3, P1, P4, P2, ti, tj);   // X2->P4, R2->P2
        ns_pass<true >(P4, P2, P3, P1, ti, tj);   // X3->P3, R3->P1
        ns_pass<true >(P3, P1, P4, P2, ti, tj);   // X4->P4, R4->P2
        ns_pass<false>(P4, P2, P3, P3, ti, tj);   // X5 = Ginv -> P3 (in place)

        wait_ge(&flags[9], 6, tid);      // b0, b2, 4 FyAT chunks done
        // stage: M1 = G1 + l*T1 (in place); R2,R4 flats; C->P2; FyAT->P1
        for (int idx = tid; idx < 1024; idx += 256) {
            int i = idx >> 4, j4 = (idx & 15) << 2;
            int o = i * 64 + j4;
            float4 gv = *(const float4*)&sM[o];
            float4 t = *(const float4*)&ws[WS_T1 + o];
            gv.x = fmaf(LMBDA, t.x, gv.x); gv.y = fmaf(LMBDA, t.y, gv.y);
            gv.z = fmaf(LMBDA, t.z, gv.z); gv.w = fmaf(LMBDA, t.w, gv.w);
            *(float4*)&sM[o] = gv;
            *(float4*)&cR2[o] = *(const float4*)&ws[WS_R2 + o];
            *(float4*)&cR4[o] = *(const float4*)&ws[WS_R4 + o];
            *(float4*)&P2[i * LDP + j4] = *(const float4*)&ws[WS_C + o];
            *(float4*)&P1[i * LDP + j4] = *(const float4*)&ws[WS_FYAT + o];
        }
        float4 eyv = *(const float4*)&ey[4 * ti];
        float eyr[4] = {eyv.x, eyv.y, eyv.z, eyv.w};
        float leyr[4];
        #pragma unroll
        for (int r = 0; r < 4; ++r) leyr[r] = LMBDA * eyr[r];

        float fyr[4][4], xreg[4][4];
        #pragma unroll
        for (int r = 0; r < 4; ++r) {
            float4 v = *(const float4*)&ws[WS_FYAT + (4 * ti + r) * 64 + 4 * tj];
            fyr[r][0] = v.x; fyr[r][1] = v.y; fyr[r][2] = v.z; fyr[r][3] = v.w;
        }
        __syncthreads();

        // free iteration 0: X1 = FyAT * Ginv (exact: grp1/grp2 vanish at X=0)
        {
            float dX[4][4] = {};
            mm64<LDP, LDP>(P1, P3, ti, tj, dX);
            #pragma unroll
            for (int r = 0; r < 4; ++r) {
                #pragma unroll
                for (int c = 0; c < 4; ++c) xreg[r][c] = dX[r][c];
                float4 v = {xreg[r][0], xreg[r][1], xreg[r][2], xreg[r][3]};
                *(float4*)&P4[(4 * ti + r) * LDP + 4 * tj] = v;
            }
        }
        __syncthreads();

        float E1[4][4];
        for (int it = 0; it < OUTER_FULL; ++it) {
            // grp1: Sm=X*M1, S2=X*R2, S4=X*R4 (shared A-reads)
            {
                float Sm[4][4] = {}, S2[4][4] = {}, S4[4][4] = {};
                #pragma unroll 2
                for (int k = 0; k < 64; k += 4) {
                    float4 av[4];
                    #pragma unroll
                    for (int r = 0; r < 4; ++r)
                        av[r] = *(const float4*)&P4[(4 * ti + r) * LDP + k];
                    #pragma unroll
                    for (int q = 0; q < 4; ++q) {
                        float4 mv = *(const float4*)&sM[(k + q) * 64 + 4 * tj];
                        float4 qv = *(const float4*)&cR2[(k + q) * 64 + 4 * tj];
                        float4 rv = *(const float4*)&cR4[(k + q) * 64 + 4 * tj];
                        #pragma unroll
                        for (int r = 0; r < 4; ++r) {
                            float x = COMP(av[r], q);
                            FMA4(Sm[r], x, mv);
                            FMA4(S2[r], x, qv);
                            FMA4(S4[r], x, rv);
                        }
                    }
                }
                __syncthreads();   // all FyAT/E2 reads of P1 done before overwrite
                #pragma unroll
                for (int r = 0; r < 4; ++r) {
                    float4 e2;
                    e2.x = LMBDA * fmaf(eyr[r], S4[r][0], -S2[r][0]);
                    e2.y = LMBDA * fmaf(eyr[r], S4[r][1], -S2[r][1]);
                    e2.z = LMBDA * fmaf(eyr[r], S4[r][2], -S2[r][2]);
                    e2.w = LMBDA * fmaf(eyr[r], S4[r][3], -S2[r][3]);
                    *(float4*)&P1[(4 * ti + r) * LDP + 4 * tj] = e2;
                    #pragma unroll
                    for (int c = 0; c < 4; ++c)
                        E1[r][c] = fmaf(-leyr[r], S2[r][c], Sm[r][c]);
                }
            }
            __syncthreads();
            // grp2: Z = C*E2 ; then W = FyAT - E1 - Z -> P1 (overwrites E2)
            {
                float Z[4][4] = {};
                mm64<LDP, LDP>(P2, P1, ti, tj, Z);
                __syncthreads();   // all E2 reads done before W overwrite
                #pragma unroll
                for (int r = 0; r < 4; ++r) {
                    float4 w;
                    w.x = fyr[r][0] - E1[r][0] - Z[r][0];
                    w.y = fyr[r][1] - E1[r][1] - Z[r][1];
                    w.z = fyr[r][2] - E1[r][2] - Z[r][2];
                    w.w = fyr[r][3] - E1[r][3] - Z[r][3];
                    *(float4*)&P1[(4 * ti + r) * LDP + 4 * tj] = w;
                }
            }
            __syncthreads();
            // grp3: dX = W*Ginv ; X += dX
            {
                float dX[4][4] = {};
                mm64<LDP, LDP>(P1, P3, ti, tj, dX);
                #pragma unroll
                for (int r = 0; r < 4; ++r) {
                    float4 v;
                    #pragma unroll
                    for (int c = 0; c < 4; ++c) xreg[r][c] += dX[r][c];
                    v.x = xreg[r][0]; v.y = xreg[r][1]; v.z = xreg[r][2]; v.w = xreg[r][3];
                    *(float4*)&P4[(4 * ti + r) * LDP + 4 * tj] = v;
                    if (it == OUTER_FULL - 1)
                        *(float4*)&out[(4 * ti + r) * 64 + 4 * tj] = v;
                }
            }
            if (it == OUTER_FULL - 1) break;
            __syncthreads();
        }
    }
}

extern "C" void kernel_launch(void* const* d_in, const int* in_sizes, int n_in,
                              void* d_out, int out_size, void* d_ws, size_t ws_size,
                              hipStream_t stream) {
    (void)in_sizes; (void)n_in; (void)out_size; (void)ws_size;
    const float* fx = (const float*)d_in[0];
    const float* fy = (const float*)d_in[1];
    const float* ex = (const float*)d_in[2];
    const float* ey = (const float*)d_in[3];
    const float* tx = (const float*)d_in[4];
    const float* ty = (const float*)d_in[5];
    const float* sx = (const float*)d_in[6];
    const float* sy = (const float*)d_in[7];
    float* ws = (float*)d_ws;
    float* out = (float*)d_out;

    (void)hipFuncSetAttribute((const void*)fused_fmnet,
                              hipFuncAttributeMaxDynamicSharedMemorySize, 134144);

    // zero A/Fy/G1/FyAT accumulators + flags
    (void)hipMemsetAsync(d_ws, 0, (size_t)(WS_T1) * sizeof(float), stream);
    (void)hipMemsetAsync((char*)d_ws + (size_t)WS_FLAGS * sizeof(float), 0, 64, stream);
    fused_fmnet<<<251, 256, 134144, stream>>>(fx, fy, ex, ey, tx, ty, sx, sy, ws, out);
}